// Round 1
// baseline (486.312 us; speedup 1.0000x reference)
//
#include <hip/hip_runtime.h>
#include <math.h>
#include <stdint.h>

typedef __bf16 bf16x8_t __attribute__((ext_vector_type(8)));
typedef float  f32x4_t  __attribute__((ext_vector_type(4)));
typedef unsigned short u16;

// ---- helpers -------------------------------------------------------------

__device__ __forceinline__ u16 f2bf(float f) {
  // round-to-nearest-even f32 -> bf16
  unsigned u = __float_as_uint(f);
  u += 0x7FFFu + ((u >> 16) & 1u);
  return (u16)(u >> 16);
}

__device__ __forceinline__ void gload_lds16(const u16* gsrc, u16* ldst) {
  // async global->LDS, 16B per lane; LDS dest = wave-uniform base + lane*16
  __builtin_amdgcn_global_load_lds(
      (__attribute__((address_space(1))) void*)(const_cast<u16*>(gsrc)),
      (__attribute__((address_space(3))) void*)(ldst),
      16, 0, 0);
}

__device__ __forceinline__ void store_out(float* C, long idx, float v) { C[idx] = v; }
__device__ __forceinline__ void store_out(u16* C, long idx, float v) { C[idx] = f2bf(v); }

__device__ __forceinline__ float alibi_slope(int h, int H) {
  // Bloom-style slopes
  int cp2 = 1, lg = 0;
  while (cp2 * 2 <= H) { cp2 *= 2; lg++; }
  if (h < cp2) {
    double e = exp2((double)-(lg - 3));          // 2^-(log2(cp2)-3)
    return (float)exp2(-e * (double)(h + 1));
  } else {
    double e = exp2((double)-(lg + 1 - 3));      // 2^-(log2(2*cp2)-3)
    return (float)exp2(-e * (double)(2 * (h - cp2) + 1));
  }
}

// ---- elementwise cast f32 -> bf16 ---------------------------------------

__global__ __launch_bounds__(256) void k_cast_bf16(const float* __restrict__ in,
                                                   u16* __restrict__ out, long n) {
  long i = ((long)blockIdx.x * 256 + threadIdx.x) * 4;
  if (i + 3 < n) {
    float4 v = *reinterpret_cast<const float4*>(in + i);
    ushort4 o;
    o.x = f2bf(v.x); o.y = f2bf(v.y); o.z = f2bf(v.z); o.w = f2bf(v.w);
    *reinterpret_cast<ushort4*>(out + i) = o;
  }
}

// ---- transpose + cast: out[z][c][r] = bf16(in[z][r][c]), RxC per matrix --

__global__ __launch_bounds__(256) void k_transpose_cast(const float* __restrict__ in,
                                                        u16* __restrict__ out,
                                                        int R, int C) {
  __shared__ float tile[32][33];
  const float* inz = in + (long)blockIdx.z * R * C;
  u16* outz = out + (long)blockIdx.z * R * C;
  const int tx = threadIdx.x & 31, ty = threadIdx.x >> 5;
  const int r0 = blockIdx.y * 32, c0 = blockIdx.x * 32;
#pragma unroll
  for (int i = 0; i < 4; ++i)
    tile[ty + i * 8][tx] = inz[(long)(r0 + ty + i * 8) * C + c0 + tx];
  __syncthreads();
#pragma unroll
  for (int i = 0; i < 4; ++i)
    outz[(long)(c0 + ty + i * 8) * R + r0 + tx] = f2bf(tile[tx][ty + i * 8]);
}

// ---- per-(b,h) transpose of V: [S,Dh slice of D] -> Vt[bh][Dh][S] --------

__global__ __launch_bounds__(256) void k_transpose_v(const u16* __restrict__ V,
                                                     u16* __restrict__ Vt,
                                                     int S, int D, int Dh, int H) {
  __shared__ u16 tile[32][33];
  const int bh = blockIdx.z, b = bh / H, h = bh % H;
  const int tx = threadIdx.x & 31, ty = threadIdx.x >> 5;
  const int s0 = blockIdx.x * 32, d0 = blockIdx.y * 32;
  const u16* vin = V + (long)b * S * D + (long)h * Dh;
#pragma unroll
  for (int i = 0; i < 4; ++i)
    tile[ty + i * 8][tx] = vin[(long)(s0 + ty + i * 8) * D + d0 + tx];
  __syncthreads();
  u16* vout = Vt + (long)bh * Dh * S;
#pragma unroll
  for (int i = 0; i < 4; ++i)
    vout[(long)(d0 + ty + i * 8) * S + s0 + tx] = tile[tx][ty + i * 8];
}

// ---- bf16 GEMM, bt pattern: C[M,N] = A[M,K] * Bt[N,K]^T ------------------
// 128x128 tile, BK=64, 4 waves (2x2), each wave 64x64 = 4x4 frags of 16x16x32.

template <typename OUT_T>
__global__ __launch_bounds__(256) void k_gemm_bt(const u16* __restrict__ A,
                                                 const u16* __restrict__ Bt,
                                                 OUT_T* __restrict__ C,
                                                 int M, int N, int K,
                                                 long strideA, long strideB, long strideC) {
  __shared__ u16 As[128][64];
  __shared__ u16 Bs[128][64];
  const int tid = threadIdx.x;
  const int wid = tid >> 6, lane = tid & 63;
  const int wr = wid >> 1, wc = wid & 1;

  A  += (long)blockIdx.z * strideA;
  Bt += (long)blockIdx.z * strideB;
  C  += (long)blockIdx.z * strideC;

  const long abase = (long)blockIdx.y * 128;
  const long bbase = (long)blockIdx.x * 128;

  f32x4_t acc[4][4];
#pragma unroll
  for (int m = 0; m < 4; ++m)
#pragma unroll
    for (int n = 0; n < 4; ++n)
#pragma unroll
      for (int r = 0; r < 4; ++r) acc[m][n][r] = 0.f;

  const int srow = lane >> 3;        // 0..7 rows per wave-issue
  const int scol = (lane & 7) * 8;   // k-granule (8 bf16 = 16B)

  for (int kt = 0; kt < K; kt += 64) {
    __syncthreads();
#pragma unroll
    for (int i = 0; i < 4; ++i) {
      const int lr = i * 32 + wid * 8;   // wave-uniform LDS row base
      gload_lds16(A  + (abase + lr + srow) * (long)K + kt + scol, &As[lr][0]);
      gload_lds16(Bt + (bbase + lr + srow) * (long)K + kt + scol, &Bs[lr][0]);
    }
    __syncthreads();

    const int frow = lane & 15;
    const int fk8  = (lane >> 4) * 8;
#pragma unroll
    for (int kk = 0; kk < 2; ++kk) {
      bf16x8_t af[4], bfr[4];
#pragma unroll
      for (int m = 0; m < 4; ++m)
        af[m] = *reinterpret_cast<const bf16x8_t*>(&As[wr * 64 + m * 16 + frow][kk * 32 + fk8]);
#pragma unroll
      for (int n = 0; n < 4; ++n)
        bfr[n] = *reinterpret_cast<const bf16x8_t*>(&Bs[wc * 64 + n * 16 + frow][kk * 32 + fk8]);
#pragma unroll
      for (int m = 0; m < 4; ++m)
#pragma unroll
        for (int n = 0; n < 4; ++n)
          acc[m][n] = __builtin_amdgcn_mfma_f32_16x16x32_bf16(af[m], bfr[n], acc[m][n], 0, 0, 0);
    }
  }

  const int orow = (lane >> 4) * 4;
  const int ocol = lane & 15;
#pragma unroll
  for (int m = 0; m < 4; ++m)
#pragma unroll
    for (int n = 0; n < 4; ++n)
#pragma unroll
      for (int r = 0; r < 4; ++r) {
        const long row = abase + wr * 64 + m * 16 + orow + r;
        const long col = bbase + wc * 64 + n * 16 + ocol;
        store_out(C, row * (long)N + col, acc[m][n][r]);
      }
}

// ---- flash attention with ALiBi + causal mask ----------------------------
// grid: (S/128, B*H). 4 waves, each owns 32 q-rows. KVBLK=64.

__global__ __launch_bounds__(256) void k_attn(const u16* __restrict__ Q,
                                              const u16* __restrict__ Kb,
                                              const u16* __restrict__ Vt,
                                              u16* __restrict__ Out,
                                              int B, int S, int H, int D, float sm_scale) {
  __shared__ u16 Ks[64][128];   // [k-local][dh]
  __shared__ u16 Vs[128][64];   // [dh][k-local]  (from Vt)
  __shared__ u16 Ps[128][64];   // [q-local][k-local]

  const int tid = threadIdx.x, wid = tid >> 6, lane = tid & 63;
  const int qb = blockIdx.x, bh = blockIdx.y;
  const int b = bh / H, h = bh % H;
  const int Dh = D / H;  // 128

  const float slope = alibi_slope(h, H);
  const long qrow0 = (long)b * S + qb * 128 + wid * 32;

  const int frow = lane & 15;
  const int fk8  = (lane >> 4) * 8;
  const int orow = (lane >> 4) * 4;
  const int ocol = lane & 15;

  // Q fragments in registers: 2 m-frags x 4 k-steps (Dh=128)
  bf16x8_t aq[2][4];
#pragma unroll
  for (int m = 0; m < 2; ++m)
#pragma unroll
    for (int kk = 0; kk < 4; ++kk)
      aq[m][kk] = *reinterpret_cast<const bf16x8_t*>(
          Q + (qrow0 + m * 16 + frow) * (long)D + h * Dh + kk * 32 + fk8);

  f32x4_t oacc[2][8];
#pragma unroll
  for (int m = 0; m < 2; ++m)
#pragma unroll
    for (int no = 0; no < 8; ++no)
#pragma unroll
      for (int r = 0; r < 4; ++r) oacc[m][no][r] = 0.f;

  float mrun[2][4], lrun[2][4];
#pragma unroll
  for (int m = 0; m < 2; ++m)
#pragma unroll
    for (int r = 0; r < 4; ++r) { mrun[m][r] = -3.0e38f; lrun[m][r] = 0.f; }

  const int qg0 = qb * 128 + wid * 32;
  const int ktiles = 2 * qb + 2;

  for (int kt = 0; kt < ktiles; ++kt) {
    __syncthreads();
    // stage K tile (64 x 128): 4 rows per wave-issue
#pragma unroll
    for (int i = 0; i < 4; ++i) {
      const int lr = i * 16 + wid * 4;
      gload_lds16(Kb + ((long)b * S + kt * 64 + lr + (lane >> 4)) * (long)D + h * Dh + (lane & 15) * 8,
                  &Ks[lr][0]);
    }
    // stage Vt tile (128 x 64): 8 rows per wave-issue
#pragma unroll
    for (int i = 0; i < 4; ++i) {
      const int lr = i * 32 + wid * 8;
      gload_lds16(Vt + ((long)bh * Dh + lr + (lane >> 3)) * (long)S + kt * 64 + (lane & 7) * 8,
                  &Vs[lr][0]);
    }
    __syncthreads();

    // S = Q K^T  (per wave: 32 x 64)
    f32x4_t sacc[2][4];
#pragma unroll
    for (int m = 0; m < 2; ++m)
#pragma unroll
      for (int n = 0; n < 4; ++n)
#pragma unroll
        for (int r = 0; r < 4; ++r) sacc[m][n][r] = 0.f;

#pragma unroll
    for (int kk = 0; kk < 4; ++kk) {
      bf16x8_t bk[4];
#pragma unroll
      for (int n = 0; n < 4; ++n)
        bk[n] = *reinterpret_cast<const bf16x8_t*>(&Ks[n * 16 + frow][kk * 32 + fk8]);
#pragma unroll
      for (int m = 0; m < 2; ++m)
#pragma unroll
        for (int n = 0; n < 4; ++n)
          sacc[m][n] = __builtin_amdgcn_mfma_f32_16x16x32_bf16(aq[m][kk], bk[n], sacc[m][n], 0, 0, 0);
    }

    // scale + alibi + causal mask + tile row-max
    float tmax[2][4];
#pragma unroll
    for (int m = 0; m < 2; ++m)
#pragma unroll
      for (int r = 0; r < 4; ++r) tmax[m][r] = -3.0e38f;

#pragma unroll
    for (int m = 0; m < 2; ++m)
#pragma unroll
      for (int n = 0; n < 4; ++n)
#pragma unroll
        for (int r = 0; r < 4; ++r) {
          const int qg = qg0 + m * 16 + orow + r;
          const int kg = kt * 64 + n * 16 + ocol;
          float v = sacc[m][n][r] * sm_scale + slope * (float)(kg - qg);
          v = (kg <= qg) ? v : -1.0e30f;
          sacc[m][n][r] = v;
          tmax[m][r] = fmaxf(tmax[m][r], v);
        }
#pragma unroll
    for (int m = 0; m < 2; ++m)
#pragma unroll
      for (int r = 0; r < 4; ++r) {
        float t = tmax[m][r];
        t = fmaxf(t, __shfl_xor(t, 1));
        t = fmaxf(t, __shfl_xor(t, 2));
        t = fmaxf(t, __shfl_xor(t, 4));
        t = fmaxf(t, __shfl_xor(t, 8));
        tmax[m][r] = t;
      }

    // online softmax update; write P to LDS as bf16
    float tsum[2][4];
#pragma unroll
    for (int m = 0; m < 2; ++m)
#pragma unroll
      for (int r = 0; r < 4; ++r) {
        const float mnew = fmaxf(mrun[m][r], tmax[m][r]);
        const float alpha = __expf(mrun[m][r] - mnew);
        mrun[m][r] = mnew;
        lrun[m][r] *= alpha;
#pragma unroll
        for (int no = 0; no < 8; ++no) oacc[m][no][r] *= alpha;
        tsum[m][r] = 0.f;
      }
#pragma unroll
    for (int m = 0; m < 2; ++m)
#pragma unroll
      for (int n = 0; n < 4; ++n)
#pragma unroll
        for (int r = 0; r < 4; ++r) {
          const float p = __expf(sacc[m][n][r] - mrun[m][r]);
          tsum[m][r] += p;
          Ps[wid * 32 + m * 16 + orow + r][n * 16 + ocol] = f2bf(p);
        }
#pragma unroll
    for (int m = 0; m < 2; ++m)
#pragma unroll
      for (int r = 0; r < 4; ++r) {
        float t = tsum[m][r];
        t += __shfl_xor(t, 1);
        t += __shfl_xor(t, 2);
        t += __shfl_xor(t, 4);
        t += __shfl_xor(t, 8);
        lrun[m][r] += t;
      }

    __syncthreads();  // P visible; Vs already staged

    // O += P V  (A-frags of P from LDS, B-frags from Vs)
#pragma unroll
    for (int kk = 0; kk < 2; ++kk) {
      bf16x8_t pa[2];
      pa[0] = *reinterpret_cast<const bf16x8_t*>(&Ps[wid * 32 + frow][kk * 32 + fk8]);
      pa[1] = *reinterpret_cast<const bf16x8_t*>(&Ps[wid * 32 + 16 + frow][kk * 32 + fk8]);
#pragma unroll
      for (int no = 0; no < 8; ++no) {
        bf16x8_t bv = *reinterpret_cast<const bf16x8_t*>(&Vs[no * 16 + frow][kk * 32 + fk8]);
        oacc[0][no] = __builtin_amdgcn_mfma_f32_16x16x32_bf16(pa[0], bv, oacc[0][no], 0, 0, 0);
        oacc[1][no] = __builtin_amdgcn_mfma_f32_16x16x32_bf16(pa[1], bv, oacc[1][no], 0, 0, 0);
      }
    }
  }

  // epilogue: divide by row sum, store bf16
#pragma unroll
  for (int m = 0; m < 2; ++m)
#pragma unroll
    for (int r = 0; r < 4; ++r) {
      const float rl = 1.0f / lrun[m][r];
      const long trow = qrow0 + m * 16 + orow + r;
#pragma unroll
      for (int no = 0; no < 8; ++no)
        Out[trow * (long)D + h * Dh + no * 16 + ocol] = f2bf(oacc[m][no][r] * rl);
    }
}

// ---- launch --------------------------------------------------------------

extern "C" void kernel_launch(void* const* d_in, const int* in_sizes, int n_in,
                              void* d_out, int out_size, void* d_ws, size_t ws_size,
                              hipStream_t stream) {
  const float* hs   = (const float*)d_in[0];
  const float* qkvw = (const float*)d_in[1];
  const float* ow   = (const float*)d_in[2];

  const int D = 2048, B = 2, H = 16;
  const long TD = (long)in_sizes[0];   // T*D = 8388608
  const long DD = (long)in_sizes[2];   // D*D = 4194304
  const int T = (int)(TD / D);         // 4096
  const int S = T / B;                 // 2048
  const int Dh = D / H;                // 128
  const float sm_scale = 1.0f / sqrtf((float)Dh);

  u16* ws  = (u16*)d_ws;
  u16* hsb = ws;                  // TD    (later reused as attn)
  u16* wt  = ws + TD;             // 3*DD  (later reused as vt)
  u16* owt = wt + 3 * DD;         // DD
  u16* qkv = owt + DD;            // 3*TD  [Q | K | V]
  u16* vt   = wt;                 // TD    (overlay; wt dead after QKV GEMM)
  u16* attn = hsb;                // TD    (overlay; hsb dead after QKV GEMM)

  // 1) hidden -> bf16
  k_cast_bf16<<<dim3((unsigned)(TD / 1024)), 256, 0, stream>>>(hs, hsb, TD);
  // 2) qkv weights: cast + transpose to [3][E][D]
  k_transpose_cast<<<dim3(D / 32, D / 32, 3), 256, 0, stream>>>(qkvw, wt, D, D);
  // 3) o_proj weight: cast + transpose to [E][D]
  k_transpose_cast<<<dim3(D / 32, D / 32, 1), 256, 0, stream>>>(ow, owt, D, D);
  // 4) QKV projection (3 batched GEMMs): qkv[c] = hsb @ wt[c]^T
  k_gemm_bt<u16><<<dim3(D / 128, T / 128, 3), 256, 0, stream>>>(
      hsb, wt, qkv, T, D, D, 0L, DD, TD);
  // 5) V -> Vt[bh][Dh][S]
  k_transpose_v<<<dim3(S / 32, Dh / 32, B * H), 256, 0, stream>>>(
      qkv + 2 * TD, vt, S, D, Dh, H);
  // 6) attention
  k_attn<<<dim3(S / 128, B * H), 256, 0, stream>>>(
      qkv, qkv + TD, vt, attn, B, S, H, D, sm_scale);
  // 7) output projection -> f32 d_out
  k_gemm_bt<float><<<dim3(D / 128, T / 128, 1), 256, 0, stream>>>(
      attn, owt, (float*)d_out, T, D, D, 0L, 0L, 0L);
}

// Round 2
// 343.312 us; speedup vs baseline: 1.4165x; 1.4165x over previous
//
#include <hip/hip_runtime.h>
#include <math.h>
#include <stdint.h>

typedef __bf16 bf16x8_t __attribute__((ext_vector_type(8)));
typedef float  f32x4_t  __attribute__((ext_vector_type(4)));
typedef unsigned short u16;

// ---- helpers -------------------------------------------------------------

__device__ __forceinline__ u16 f2bf(float f) {
  // round-to-nearest-even f32 -> bf16
  unsigned u = __float_as_uint(f);
  u += 0x7FFFu + ((u >> 16) & 1u);
  return (u16)(u >> 16);
}

__device__ __forceinline__ void gload_lds16(const u16* gsrc, u16* ldst) {
  // async global->LDS, 16B per lane; LDS dest = wave-uniform base + lane*16
  __builtin_amdgcn_global_load_lds(
      (__attribute__((address_space(1))) void*)(const_cast<u16*>(gsrc)),
      (__attribute__((address_space(3))) void*)(ldst),
      16, 0, 0);
}

// XOR bank-conflict swizzle (G4 recipe): byte ^= ((row&7)<<4) == elem ^= ((row&7)<<3)
__device__ __forceinline__ int sw8(int row, int e) { return e ^ ((row & 7) << 3); }

__device__ __forceinline__ void store_out(float* C, long idx, float v) { C[idx] = v; }
__device__ __forceinline__ void store_out(u16* C, long idx, float v) { C[idx] = f2bf(v); }

__device__ __forceinline__ float alibi_slope(int h, int H) {
  // Bloom-style slopes
  int cp2 = 1, lg = 0;
  while (cp2 * 2 <= H) { cp2 *= 2; lg++; }
  if (h < cp2) {
    double e = exp2((double)-(lg - 3));          // 2^-(log2(cp2)-3)
    return (float)exp2(-e * (double)(h + 1));
  } else {
    double e = exp2((double)-(lg + 1 - 3));      // 2^-(log2(2*cp2)-3)
    return (float)exp2(-e * (double)(2 * (h - cp2) + 1));
  }
}

// ---- elementwise cast f32 -> bf16 ---------------------------------------

__global__ __launch_bounds__(256) void k_cast_bf16(const float* __restrict__ in,
                                                   u16* __restrict__ out, long n) {
  long i = ((long)blockIdx.x * 256 + threadIdx.x) * 4;
  if (i + 3 < n) {
    float4 v = *reinterpret_cast<const float4*>(in + i);
    ushort4 o;
    o.x = f2bf(v.x); o.y = f2bf(v.y); o.z = f2bf(v.z); o.w = f2bf(v.w);
    *reinterpret_cast<ushort4*>(out + i) = o;
  }
}

// ---- transpose + cast: out[z][c][r] = bf16(in[z][r][c]), RxC per matrix --

__global__ __launch_bounds__(256) void k_transpose_cast(const float* __restrict__ in,
                                                        u16* __restrict__ out,
                                                        int R, int C) {
  __shared__ float tile[32][33];
  const float* inz = in + (long)blockIdx.z * R * C;
  u16* outz = out + (long)blockIdx.z * R * C;
  const int tx = threadIdx.x & 31, ty = threadIdx.x >> 5;
  const int r0 = blockIdx.y * 32, c0 = blockIdx.x * 32;
#pragma unroll
  for (int i = 0; i < 4; ++i)
    tile[ty + i * 8][tx] = inz[(long)(r0 + ty + i * 8) * C + c0 + tx];
  __syncthreads();
#pragma unroll
  for (int i = 0; i < 4; ++i)
    outz[(long)(c0 + ty + i * 8) * R + r0 + tx] = f2bf(tile[tx][ty + i * 8]);
}

// ---- per-(b,h) transpose of V: [S,Dh slice of D] -> Vt[bh][Dh][S] --------

__global__ __launch_bounds__(256) void k_transpose_v(const u16* __restrict__ V,
                                                     u16* __restrict__ Vt,
                                                     int S, int D, int Dh, int H) {
  __shared__ u16 tile[32][33];
  const int bh = blockIdx.z, b = bh / H, h = bh % H;
  const int tx = threadIdx.x & 31, ty = threadIdx.x >> 5;
  const int s0 = blockIdx.x * 32, d0 = blockIdx.y * 32;
  const u16* vin = V + (long)b * S * D + (long)h * Dh;
#pragma unroll
  for (int i = 0; i < 4; ++i)
    tile[ty + i * 8][tx] = vin[(long)(s0 + ty + i * 8) * D + d0 + tx];
  __syncthreads();
  u16* vout = Vt + (long)bh * Dh * S;
#pragma unroll
  for (int i = 0; i < 4; ++i)
    vout[(long)(d0 + ty + i * 8) * S + s0 + tx] = tile[tx][ty + i * 8];
}

// ---- bf16 GEMM, bt pattern: C[M,N] = A[M,K] * Bt[N,K]^T ------------------
// 128x128 tile, BK=64, 4 waves (2x2), each wave 64x64 = 4x4 frags of 16x16x32.

template <typename OUT_T>
__global__ __launch_bounds__(256) void k_gemm_bt(const u16* __restrict__ A,
                                                 const u16* __restrict__ Bt,
                                                 OUT_T* __restrict__ C,
                                                 int M, int N, int K,
                                                 long strideA, long strideB, long strideC) {
  __shared__ u16 As[128][64];
  __shared__ u16 Bs[128][64];
  const int tid = threadIdx.x;
  const int wid = tid >> 6, lane = tid & 63;
  const int wr = wid >> 1, wc = wid & 1;

  A  += (long)blockIdx.z * strideA;
  Bt += (long)blockIdx.z * strideB;
  C  += (long)blockIdx.z * strideC;

  const long abase = (long)blockIdx.y * 128;
  const long bbase = (long)blockIdx.x * 128;

  f32x4_t acc[4][4];
#pragma unroll
  for (int m = 0; m < 4; ++m)
#pragma unroll
    for (int n = 0; n < 4; ++n)
#pragma unroll
      for (int r = 0; r < 4; ++r) acc[m][n][r] = 0.f;

  const int srow = lane >> 3;        // 0..7 rows per wave-issue
  const int scol = (lane & 7) * 8;   // k-granule (8 bf16 = 16B)

  for (int kt = 0; kt < K; kt += 64) {
    __syncthreads();
#pragma unroll
    for (int i = 0; i < 4; ++i) {
      const int lr = i * 32 + wid * 8;   // wave-uniform LDS row base
      gload_lds16(A  + (abase + lr + srow) * (long)K + kt + scol, &As[lr][0]);
      gload_lds16(Bt + (bbase + lr + srow) * (long)K + kt + scol, &Bs[lr][0]);
    }
    __syncthreads();

    const int frow = lane & 15;
    const int fk8  = (lane >> 4) * 8;
#pragma unroll
    for (int kk = 0; kk < 2; ++kk) {
      bf16x8_t af[4], bfr[4];
#pragma unroll
      for (int m = 0; m < 4; ++m)
        af[m] = *reinterpret_cast<const bf16x8_t*>(&As[wr * 64 + m * 16 + frow][kk * 32 + fk8]);
#pragma unroll
      for (int n = 0; n < 4; ++n)
        bfr[n] = *reinterpret_cast<const bf16x8_t*>(&Bs[wc * 64 + n * 16 + frow][kk * 32 + fk8]);
#pragma unroll
      for (int m = 0; m < 4; ++m)
#pragma unroll
        for (int n = 0; n < 4; ++n)
          acc[m][n] = __builtin_amdgcn_mfma_f32_16x16x32_bf16(af[m], bfr[n], acc[m][n], 0, 0, 0);
    }
  }

  const int orow = (lane >> 4) * 4;
  const int ocol = lane & 15;
#pragma unroll
  for (int m = 0; m < 4; ++m)
#pragma unroll
    for (int n = 0; n < 4; ++n)
#pragma unroll
      for (int r = 0; r < 4; ++r) {
        const long row = abase + wr * 64 + m * 16 + orow + r;
        const long col = bbase + wc * 64 + n * 16 + ocol;
        store_out(C, row * (long)N + col, acc[m][n][r]);
      }
}

// ---- flash attention with ALiBi + causal mask ----------------------------
// grid: (S/128, B*H). 4 waves, each owns 32 q-rows. KVBLK=64.
// LDS tiles XOR-swizzled (G4): stage via inverse-swizzled global source
// (rule #21: linear gload_lds dest + swz source + swz read).

__global__ __launch_bounds__(256) void k_attn(const u16* __restrict__ Q,
                                              const u16* __restrict__ Kb,
                                              const u16* __restrict__ Vt,
                                              u16* __restrict__ Out,
                                              int B, int S, int H, int D, float sm_scale) {
  __shared__ u16 Ks[64][128];   // [k-local][dh]      (swizzled)
  __shared__ u16 Vs[128][64];   // [dh][k-local]      (swizzled, from Vt)
  __shared__ u16 Ps[128][64];   // [q-local][k-local] (swizzled)

  const int tid = threadIdx.x, wid = tid >> 6, lane = tid & 63;

  // Work-pairing remap: colocated blocks (lin and lin+gridTotal/2) get qb and
  // nq-1-qb so every CU carries ~constant causal work (2qb+2 + 2(nq-1-qb)+2).
  const int nq = gridDim.x, nbh = gridDim.y;
  const int lin = blockIdx.x + nq * blockIdx.y;
  const int qb0 = lin / nbh;
  const int bh  = lin % nbh;
  const int qb  = (qb0 < nq / 2) ? qb0 : (nq + nq / 2 - 1 - qb0);

  const int b = bh / H, h = bh % H;
  const int Dh = D / H;  // 128

  const float slope = alibi_slope(h, H);
  const long qrow0 = (long)b * S + qb * 128 + wid * 32;

  const int frow = lane & 15;
  const int fk8  = (lane >> 4) * 8;
  const int orow = (lane >> 4) * 4;
  const int ocol = lane & 15;

  // Q fragments in registers: 2 m-frags x 4 k-steps (Dh=128)
  bf16x8_t aq[2][4];
#pragma unroll
  for (int m = 0; m < 2; ++m)
#pragma unroll
    for (int kk = 0; kk < 4; ++kk)
      aq[m][kk] = *reinterpret_cast<const bf16x8_t*>(
          Q + (qrow0 + m * 16 + frow) * (long)D + h * Dh + kk * 32 + fk8);

  f32x4_t oacc[2][8];
#pragma unroll
  for (int m = 0; m < 2; ++m)
#pragma unroll
    for (int no = 0; no < 8; ++no)
#pragma unroll
      for (int r = 0; r < 4; ++r) oacc[m][no][r] = 0.f;

  float mrun[2][4], lrun[2][4];
#pragma unroll
  for (int m = 0; m < 2; ++m)
#pragma unroll
    for (int r = 0; r < 4; ++r) { mrun[m][r] = -3.0e38f; lrun[m][r] = 0.f; }

  const int qg0 = qb * 128 + wid * 32;
  const int ktiles = 2 * qb + 2;

  for (int kt = 0; kt < ktiles; ++kt) {
    __syncthreads();
    // stage K tile (64 x 128): 4 rows per wave-issue, swizzled source
#pragma unroll
    for (int i = 0; i < 4; ++i) {
      const int lr = i * 16 + wid * 4;
      const int r  = lr + (lane >> 4);
      gload_lds16(Kb + ((long)b * S + kt * 64 + r) * (long)D + h * Dh + sw8(r, (lane & 15) * 8),
                  &Ks[lr][0]);
    }
    // stage Vt tile (128 x 64): 8 rows per wave-issue, swizzled source
#pragma unroll
    for (int i = 0; i < 4; ++i) {
      const int lr = i * 32 + wid * 8;
      const int r  = lr + (lane >> 3);
      gload_lds16(Vt + ((long)bh * Dh + r) * (long)S + kt * 64 + sw8(r, (lane & 7) * 8),
                  &Vs[lr][0]);
    }
    __syncthreads();

    // wave-level skip of fully-masked tiles (waves 0,1 on the last k-tile)
    const bool active = (kt * 64) <= (qg0 + 31);

    if (active) {
      // S = Q K^T  (per wave: 32 x 64)
      f32x4_t sacc[2][4];
#pragma unroll
      for (int m = 0; m < 2; ++m)
#pragma unroll
        for (int n = 0; n < 4; ++n)
#pragma unroll
          for (int r = 0; r < 4; ++r) sacc[m][n][r] = 0.f;

#pragma unroll
      for (int kk = 0; kk < 4; ++kk) {
        bf16x8_t bk[4];
#pragma unroll
        for (int n = 0; n < 4; ++n) {
          const int krow = n * 16 + frow;
          bk[n] = *reinterpret_cast<const bf16x8_t*>(&Ks[krow][sw8(krow, kk * 32 + fk8)]);
        }
#pragma unroll
        for (int m = 0; m < 2; ++m)
#pragma unroll
          for (int n = 0; n < 4; ++n)
            sacc[m][n] = __builtin_amdgcn_mfma_f32_16x16x32_bf16(aq[m][kk], bk[n], sacc[m][n], 0, 0, 0);
      }

      // scale + alibi + causal mask + tile row-max
      float tmax[2][4];
#pragma unroll
      for (int m = 0; m < 2; ++m)
#pragma unroll
        for (int r = 0; r < 4; ++r) tmax[m][r] = -3.0e38f;

#pragma unroll
      for (int m = 0; m < 2; ++m)
#pragma unroll
        for (int n = 0; n < 4; ++n)
#pragma unroll
          for (int r = 0; r < 4; ++r) {
            const int qg = qg0 + m * 16 + orow + r;
            const int kg = kt * 64 + n * 16 + ocol;
            float v = sacc[m][n][r] * sm_scale + slope * (float)(kg - qg);
            v = (kg <= qg) ? v : -1.0e30f;
            sacc[m][n][r] = v;
            tmax[m][r] = fmaxf(tmax[m][r], v);
          }
#pragma unroll
      for (int m = 0; m < 2; ++m)
#pragma unroll
        for (int r = 0; r < 4; ++r) {
          float t = tmax[m][r];
          t = fmaxf(t, __shfl_xor(t, 1));
          t = fmaxf(t, __shfl_xor(t, 2));
          t = fmaxf(t, __shfl_xor(t, 4));
          t = fmaxf(t, __shfl_xor(t, 8));
          tmax[m][r] = t;
        }

      // online softmax update; write P to LDS as bf16 (swizzled)
      float tsum[2][4];
#pragma unroll
      for (int m = 0; m < 2; ++m)
#pragma unroll
        for (int r = 0; r < 4; ++r) {
          const float mnew = fmaxf(mrun[m][r], tmax[m][r]);
          const float alpha = __expf(mrun[m][r] - mnew);
          mrun[m][r] = mnew;
          lrun[m][r] *= alpha;
#pragma unroll
          for (int no = 0; no < 8; ++no) oacc[m][no][r] *= alpha;
          tsum[m][r] = 0.f;
        }
#pragma unroll
      for (int m = 0; m < 2; ++m)
#pragma unroll
        for (int n = 0; n < 4; ++n)
#pragma unroll
          for (int r = 0; r < 4; ++r) {
            const float p = __expf(sacc[m][n][r] - mrun[m][r]);
            tsum[m][r] += p;
            const int prow = wid * 32 + m * 16 + orow + r;
            Ps[prow][sw8(prow, n * 16 + ocol)] = f2bf(p);
          }
#pragma unroll
      for (int m = 0; m < 2; ++m)
#pragma unroll
        for (int r = 0; r < 4; ++r) {
          float t = tsum[m][r];
          t += __shfl_xor(t, 1);
          t += __shfl_xor(t, 2);
          t += __shfl_xor(t, 4);
          t += __shfl_xor(t, 8);
          lrun[m][r] += t;
        }
    }

    __syncthreads();  // P visible; Vs already staged

    if (active) {
      // O += P V  (A-frags of P from LDS, B-frags from Vs)
#pragma unroll
      for (int kk = 0; kk < 2; ++kk) {
        bf16x8_t pa[2];
        const int prow0 = wid * 32 + frow;
        const int prow1 = wid * 32 + 16 + frow;
        pa[0] = *reinterpret_cast<const bf16x8_t*>(&Ps[prow0][sw8(prow0, kk * 32 + fk8)]);
        pa[1] = *reinterpret_cast<const bf16x8_t*>(&Ps[prow1][sw8(prow1, kk * 32 + fk8)]);
#pragma unroll
        for (int no = 0; no < 8; ++no) {
          const int vrow = no * 16 + frow;
          bf16x8_t bv = *reinterpret_cast<const bf16x8_t*>(&Vs[vrow][sw8(vrow, kk * 32 + fk8)]);
          oacc[0][no] = __builtin_amdgcn_mfma_f32_16x16x32_bf16(pa[0], bv, oacc[0][no], 0, 0, 0);
          oacc[1][no] = __builtin_amdgcn_mfma_f32_16x16x32_bf16(pa[1], bv, oacc[1][no], 0, 0, 0);
        }
      }
    }
  }

  // epilogue: divide by row sum, store bf16
#pragma unroll
  for (int m = 0; m < 2; ++m)
#pragma unroll
    for (int r = 0; r < 4; ++r) {
      const float rl = 1.0f / lrun[m][r];
      const long trow = qrow0 + m * 16 + orow + r;
#pragma unroll
      for (int no = 0; no < 8; ++no)
        Out[trow * (long)D + h * Dh + no * 16 + ocol] = f2bf(oacc[m][no][r] * rl);
    }
}

// ---- launch --------------------------------------------------------------

extern "C" void kernel_launch(void* const* d_in, const int* in_sizes, int n_in,
                              void* d_out, int out_size, void* d_ws, size_t ws_size,
                              hipStream_t stream) {
  const float* hs   = (const float*)d_in[0];
  const float* qkvw = (const float*)d_in[1];
  const float* ow   = (const float*)d_in[2];

  const int D = 2048, B = 2, H = 16;
  const long TD = (long)in_sizes[0];   // T*D = 8388608
  const long DD = (long)in_sizes[2];   // D*D = 4194304
  const int T = (int)(TD / D);         // 4096
  const int S = T / B;                 // 2048
  const int Dh = D / H;                // 128
  const float sm_scale = 1.0f / sqrtf((float)Dh);

  u16* ws  = (u16*)d_ws;
  u16* hsb = ws;                  // TD    (later reused as attn)
  u16* wt  = ws + TD;             // 3*DD  (later reused as vt)
  u16* owt = wt + 3 * DD;         // DD
  u16* qkv = owt + DD;            // 3*TD  [Q | K | V]
  u16* vt   = wt;                 // TD    (overlay; wt dead after QKV GEMM)
  u16* attn = hsb;                // TD    (overlay; hsb dead after QKV GEMM)

  // 1) hidden -> bf16
  k_cast_bf16<<<dim3((unsigned)(TD / 1024)), 256, 0, stream>>>(hs, hsb, TD);
  // 2) qkv weights: cast + transpose to [3][E][D]
  k_transpose_cast<<<dim3(D / 32, D / 32, 3), 256, 0, stream>>>(qkvw, wt, D, D);
  // 3) o_proj weight: cast + transpose to [E][D]
  k_transpose_cast<<<dim3(D / 32, D / 32, 1), 256, 0, stream>>>(ow, owt, D, D);
  // 4) QKV projection (3 batched GEMMs): qkv[c] = hsb @ wt[c]^T
  k_gemm_bt<u16><<<dim3(D / 128, T / 128, 3), 256, 0, stream>>>(
      hsb, wt, qkv, T, D, D, 0L, DD, TD);
  // 5) V -> Vt[bh][Dh][S]
  k_transpose_v<<<dim3(S / 32, Dh / 32, B * H), 256, 0, stream>>>(
      qkv + 2 * TD, vt, S, D, Dh, H);
  // 6) attention
  k_attn<<<dim3(S / 128, B * H), 256, 0, stream>>>(
      qkv, qkv + TD, vt, attn, B, S, H, D, sm_scale);
  // 7) output projection -> f32 d_out
  k_gemm_bt<float><<<dim3(D / 128, T / 128, 1), 256, 0, stream>>>(
      attn, owt, (float*)d_out, T, D, D, 0L, 0L, 0L);
}

// Round 3
// 332.819 us; speedup vs baseline: 1.4612x; 1.0315x over previous
//
#include <hip/hip_runtime.h>
#include <math.h>
#include <stdint.h>

typedef __bf16 bf16x8_t __attribute__((ext_vector_type(8)));
typedef float  f32x4_t  __attribute__((ext_vector_type(4)));
typedef unsigned short u16;

// ---- helpers -------------------------------------------------------------

__device__ __forceinline__ u16 f2bf(float f) {
  unsigned u = __float_as_uint(f);
  u += 0x7FFFu + ((u >> 16) & 1u);
  return (u16)(u >> 16);
}

__device__ __forceinline__ void gload_lds16(const u16* gsrc, u16* ldst) {
  // async global->LDS, 16B per lane; LDS dest = wave-uniform base + lane*16
  __builtin_amdgcn_global_load_lds(
      (__attribute__((address_space(1))) void*)(const_cast<u16*>(gsrc)),
      (__attribute__((address_space(3))) void*)(ldst),
      16, 0, 0);
}

// XOR bank-conflict swizzle: byte ^= ((row&7)<<4) == elem ^= ((row&7)<<3)
__device__ __forceinline__ int sw8(int row, int e) { return e ^ ((row & 7) << 3); }

__device__ __forceinline__ void store_out(float* C, long idx, float v) { C[idx] = v; }
__device__ __forceinline__ void store_out(u16* C, long idx, float v) { C[idx] = f2bf(v); }

__device__ __forceinline__ float alibi_slope(int h, int H) {
  int cp2 = 1, lg = 0;
  while (cp2 * 2 <= H) { cp2 *= 2; lg++; }
  if (h < cp2) {
    double e = exp2((double)-(lg - 3));
    return (float)exp2(-e * (double)(h + 1));
  } else {
    double e = exp2((double)-(lg + 1 - 3));
    return (float)exp2(-e * (double)(2 * (h - cp2) + 1));
  }
}

#define FENCE() asm volatile("" ::: "memory")
#define BARRIER() do { FENCE(); __builtin_amdgcn_s_barrier(); \
                       __builtin_amdgcn_sched_barrier(0); FENCE(); } while (0)
#define WAITLGKM() do { asm volatile("s_waitcnt lgkmcnt(0)" ::: "memory"); \
                        __builtin_amdgcn_sched_barrier(0); } while (0)

// ---- elementwise cast f32 -> bf16 ---------------------------------------

__global__ __launch_bounds__(256) void k_cast_bf16(const float* __restrict__ in,
                                                   u16* __restrict__ out, long n) {
  long i = ((long)blockIdx.x * 256 + threadIdx.x) * 4;
  if (i + 3 < n) {
    float4 v = *reinterpret_cast<const float4*>(in + i);
    ushort4 o;
    o.x = f2bf(v.x); o.y = f2bf(v.y); o.z = f2bf(v.z); o.w = f2bf(v.w);
    *reinterpret_cast<ushort4*>(out + i) = o;
  }
}

// ---- transpose + cast: out[z][c][r] = bf16(in[z][r][c]) ------------------

__global__ __launch_bounds__(256) void k_transpose_cast(const float* __restrict__ in,
                                                        u16* __restrict__ out,
                                                        int R, int C) {
  __shared__ float tile[32][33];
  const float* inz = in + (long)blockIdx.z * R * C;
  u16* outz = out + (long)blockIdx.z * R * C;
  const int tx = threadIdx.x & 31, ty = threadIdx.x >> 5;
  const int r0 = blockIdx.y * 32, c0 = blockIdx.x * 32;
#pragma unroll
  for (int i = 0; i < 4; ++i)
    tile[ty + i * 8][tx] = inz[(long)(r0 + ty + i * 8) * C + c0 + tx];
  __syncthreads();
#pragma unroll
  for (int i = 0; i < 4; ++i)
    outz[(long)(c0 + ty + i * 8) * R + r0 + tx] = f2bf(tile[tx][ty + i * 8]);
}

// ---- per-(b,h) transpose of V: [S,Dh slice of D] -> Vt[bh][Dh][S] --------

__global__ __launch_bounds__(256) void k_transpose_v(const u16* __restrict__ V,
                                                     u16* __restrict__ Vt,
                                                     int S, int D, int Dh, int H) {
  __shared__ u16 tile[32][33];
  const int bh = blockIdx.z, b = bh / H, h = bh % H;
  const int tx = threadIdx.x & 31, ty = threadIdx.x >> 5;
  const int s0 = blockIdx.x * 32, d0 = blockIdx.y * 32;
  const u16* vin = V + (long)b * S * D + (long)h * Dh;
#pragma unroll
  for (int i = 0; i < 4; ++i)
    tile[ty + i * 8][tx] = vin[(long)(s0 + ty + i * 8) * D + d0 + tx];
  __syncthreads();
  u16* vout = Vt + (long)bh * Dh * S;
#pragma unroll
  for (int i = 0; i < 4; ++i)
    vout[(long)(d0 + ty + i * 8) * S + s0 + tx] = tile[tx][ty + i * 8];
}

// ---- 256x256 8-phase bf16 GEMM (T1+T2+T3+T4+T5), bt pattern --------------
// C[M,N] = A[M,K] * Bt[N,K]^T. 8 waves (2M x 4N), wave tile 128x64.
// LDS 128 KiB: double-buffered 256x64 tiles for A and B (XOR-swizzled via
// inverse-swizzled global source, rule #21). Per K-tile: 4 quadrant phases
// x 16 MFMA; 2 gload_lds issues/phase stage the NEXT tile into the dead
// buffer; counted vmcnt at phase-2/phase-4 closing barriers (never 0).
// Epilogue maps col -> (mat = col>>11, e = col&2047) for fused-QKV output.

__device__ __forceinline__ void stage16(const u16* __restrict__ g, long grow0, int K,
                                        int kt, int lr0, u16 (*lds)[64], int lane) {
  const int e = (lane & 7) * 8;
#pragma unroll
  for (int i = 0; i < 2; ++i) {
    const int r = lr0 + i * 8 + (lane >> 3);
    gload_lds16(g + (grow0 + r) * (long)K + kt + (e ^ ((r & 7) << 3)), &lds[lr0 + i * 8][0]);
  }
}

template <typename OUT_T>
__global__ __launch_bounds__(512, 2) void k_gemm8(const u16* __restrict__ A,
                                                  const u16* __restrict__ Bt,
                                                  OUT_T* __restrict__ Cb,
                                                  int M, int N, int K, long matStride) {
  __shared__ u16 As[2][256][64];
  __shared__ u16 Bs[2][256][64];

  const int tid = threadIdx.x, wid = tid >> 6, lane = tid & 63;
  const int wr = wid >> 2, wc = wid & 3;
  const int frow = lane & 15, fk8 = (lane >> 4) * 8;
  const int orow = (lane >> 4) * 4, ocol = lane & 15;

  // T1: bijective XCD-aware swizzle
  const int nwg = gridDim.x * gridDim.y;
  const int orig = blockIdx.y * gridDim.x + blockIdx.x;
  const int q = nwg >> 3, rr = nwg & 7;
  const int xcd = orig & 7, sl = orig >> 3;
  const int wg = (xcd < rr ? xcd * (q + 1) : rr * (q + 1) + (xcd - rr) * q) + sl;
  const int by = wg / gridDim.x, bx = wg % gridDim.x;

  const long abase = (long)by * 256, bbase = (long)bx * 256;

  // per-wave staging row bases (8 waves cover 256 rows in 16-row slices)
  const int bg0 = (wid >> 1) * 64 + (wid & 1) * 16;   // B: ph1 rows; +32 = ph2 rows
  const int ag0 = (wid >> 2) * 128 + (wid & 3) * 16;  // A: ph3 rows; +64 = ph4 rows

  f32x4_t acc[8][4];
#pragma unroll
  for (int m = 0; m < 8; ++m)
#pragma unroll
    for (int n = 0; n < 4; ++n)
#pragma unroll
      for (int r = 0; r < 4; ++r) acc[m][n][r] = 0.f;

  const int nt = K >> 6;

  // prologue: stage tile 0 into buffer 0 (issue order fixes vmcnt counting)
  stage16(Bt, bbase, K, 0, bg0, Bs[0], lane);
  stage16(Bt, bbase, K, 0, bg0 + 32, Bs[0], lane);
  stage16(A, abase, K, 0, ag0, As[0], lane);
  stage16(A, abase, K, 0, ag0 + 64, As[0], lane);
  asm volatile("s_waitcnt vmcnt(2)" ::: "memory");  // allow A-G3(0) in flight
  BARRIER();

  bf16x8_t afr[4][2], bfr[4][2];
  int cur = 0;

  for (int t = 0; t < nt; ++t) {
    const int ktn = (t + 1) << 6;
    const bool hn = (t + 1 < nt);
    const int nb = cur ^ 1;

    // ---- phase 1: quadrant (mh0, nh0) ------------------------------------
#pragma unroll
    for (int m = 0; m < 4; ++m) {
      const int r = wr * 128 + m * 16 + frow;
      afr[m][0] = *reinterpret_cast<const bf16x8_t*>(&As[cur][r][sw8(r, fk8)]);
      afr[m][1] = *reinterpret_cast<const bf16x8_t*>(&As[cur][r][sw8(r, 32 + fk8)]);
    }
#pragma unroll
    for (int n = 0; n < 2; ++n) {
      const int r = wc * 64 + n * 16 + frow;
      bfr[n][0] = *reinterpret_cast<const bf16x8_t*>(&Bs[cur][r][sw8(r, fk8)]);
      bfr[n][1] = *reinterpret_cast<const bf16x8_t*>(&Bs[cur][r][sw8(r, 32 + fk8)]);
    }
    if (hn) stage16(Bt, bbase, K, ktn, bg0, Bs[nb], lane);
    BARRIER();
    WAITLGKM();
    __builtin_amdgcn_s_setprio(1);
#pragma unroll
    for (int m = 0; m < 4; ++m)
#pragma unroll
      for (int n = 0; n < 2; ++n) {
        acc[m][n] = __builtin_amdgcn_mfma_f32_16x16x32_bf16(afr[m][0], bfr[n][0], acc[m][n], 0, 0, 0);
        acc[m][n] = __builtin_amdgcn_mfma_f32_16x16x32_bf16(afr[m][1], bfr[n][1], acc[m][n], 0, 0, 0);
      }
    __builtin_amdgcn_s_setprio(0);
    BARRIER();

    // ---- phase 2: quadrant (mh0, nh1) ------------------------------------
#pragma unroll
    for (int n = 0; n < 2; ++n) {
      const int r = wc * 64 + 32 + n * 16 + frow;
      bfr[2 + n][0] = *reinterpret_cast<const bf16x8_t*>(&Bs[cur][r][sw8(r, fk8)]);
      bfr[2 + n][1] = *reinterpret_cast<const bf16x8_t*>(&Bs[cur][r][sw8(r, 32 + fk8)]);
    }
    if (hn) stage16(Bt, bbase, K, ktn, bg0 + 32, Bs[nb], lane);
    BARRIER();
    WAITLGKM();
    __builtin_amdgcn_s_setprio(1);
#pragma unroll
    for (int m = 0; m < 4; ++m)
#pragma unroll
      for (int n = 0; n < 2; ++n) {
        acc[m][2 + n] = __builtin_amdgcn_mfma_f32_16x16x32_bf16(afr[m][0], bfr[2 + n][0], acc[m][2 + n], 0, 0, 0);
        acc[m][2 + n] = __builtin_amdgcn_mfma_f32_16x16x32_bf16(afr[m][1], bfr[2 + n][1], acc[m][2 + n], 0, 0, 0);
      }
    __builtin_amdgcn_s_setprio(0);
    // guard A rows for phase 3 (issued last tile's ph4); counted, 0 only on last tile
    if (hn) asm volatile("s_waitcnt vmcnt(4)" ::: "memory");
    else    asm volatile("s_waitcnt vmcnt(0)" ::: "memory");
    BARRIER();

    // ---- phase 3: quadrant (mh1, nh0) ------------------------------------
#pragma unroll
    for (int m = 0; m < 4; ++m) {
      const int r = wr * 128 + 64 + m * 16 + frow;
      afr[m][0] = *reinterpret_cast<const bf16x8_t*>(&As[cur][r][sw8(r, fk8)]);
      afr[m][1] = *reinterpret_cast<const bf16x8_t*>(&As[cur][r][sw8(r, 32 + fk8)]);
    }
    if (hn) stage16(A, abase, K, ktn, ag0, As[nb], lane);
    BARRIER();
    WAITLGKM();
    __builtin_amdgcn_s_setprio(1);
#pragma unroll
    for (int m = 0; m < 4; ++m)
#pragma unroll
      for (int n = 0; n < 2; ++n) {
        acc[4 + m][n] = __builtin_amdgcn_mfma_f32_16x16x32_bf16(afr[m][0], bfr[n][0], acc[4 + m][n], 0, 0, 0);
        acc[4 + m][n] = __builtin_amdgcn_mfma_f32_16x16x32_bf16(afr[m][1], bfr[n][1], acc[4 + m][n], 0, 0, 0);
      }
    __builtin_amdgcn_s_setprio(0);
    BARRIER();

    // ---- phase 4: quadrant (mh1, nh1) ------------------------------------
    if (hn) stage16(A, abase, K, ktn, ag0 + 64, As[nb], lane);
    __builtin_amdgcn_s_setprio(1);
#pragma unroll
    for (int m = 0; m < 4; ++m)
#pragma unroll
      for (int n = 0; n < 2; ++n) {
        acc[4 + m][2 + n] = __builtin_amdgcn_mfma_f32_16x16x32_bf16(afr[m][0], bfr[2 + n][0], acc[4 + m][2 + n], 0, 0, 0);
        acc[4 + m][2 + n] = __builtin_amdgcn_mfma_f32_16x16x32_bf16(afr[m][1], bfr[2 + n][1], acc[4 + m][2 + n], 0, 0, 0);
      }
    __builtin_amdgcn_s_setprio(0);
    // tile boundary: land B-G1,B-G2,A-G1 of next tile; leave A-G3 in flight
    if (hn) asm volatile("s_waitcnt vmcnt(2)" ::: "memory");
    BARRIER();

    cur ^= 1;
  }

  // epilogue: C write; col -> (mat, e) split for fused outputs
#pragma unroll
  for (int m = 0; m < 8; ++m)
#pragma unroll
    for (int n = 0; n < 4; ++n)
#pragma unroll
      for (int r = 0; r < 4; ++r) {
        const long row = abase + wr * 128 + m * 16 + orow + r;
        const int col = (int)bbase + wc * 64 + n * 16 + ocol;
        const long idx = (long)(col >> 11) * matStride + row * 2048 + (col & 2047);
        store_out(Cb, idx, acc[m][n][r]);
      }
}

// ---- flash attention with ALiBi + causal mask (unchanged, passing) -------

__global__ __launch_bounds__(256) void k_attn(const u16* __restrict__ Q,
                                              const u16* __restrict__ Kb,
                                              const u16* __restrict__ Vt,
                                              u16* __restrict__ Out,
                                              int B, int S, int H, int D, float sm_scale) {
  __shared__ u16 Ks[64][128];
  __shared__ u16 Vs[128][64];
  __shared__ u16 Ps[128][64];

  const int tid = threadIdx.x, wid = tid >> 6, lane = tid & 63;

  const int nq = gridDim.x, nbh = gridDim.y;
  const int lin = blockIdx.x + nq * blockIdx.y;
  const int qb0 = lin / nbh;
  const int bh  = lin % nbh;
  const int qb  = (qb0 < nq / 2) ? qb0 : (nq + nq / 2 - 1 - qb0);

  const int b = bh / H, h = bh % H;
  const int Dh = D / H;

  const float slope = alibi_slope(h, H);
  const long qrow0 = (long)b * S + qb * 128 + wid * 32;

  const int frow = lane & 15;
  const int fk8  = (lane >> 4) * 8;
  const int orow = (lane >> 4) * 4;
  const int ocol = lane & 15;

  bf16x8_t aq[2][4];
#pragma unroll
  for (int m = 0; m < 2; ++m)
#pragma unroll
    for (int kk = 0; kk < 4; ++kk)
      aq[m][kk] = *reinterpret_cast<const bf16x8_t*>(
          Q + (qrow0 + m * 16 + frow) * (long)D + h * Dh + kk * 32 + fk8);

  f32x4_t oacc[2][8];
#pragma unroll
  for (int m = 0; m < 2; ++m)
#pragma unroll
    for (int no = 0; no < 8; ++no)
#pragma unroll
      for (int r = 0; r < 4; ++r) oacc[m][no][r] = 0.f;

  float mrun[2][4], lrun[2][4];
#pragma unroll
  for (int m = 0; m < 2; ++m)
#pragma unroll
    for (int r = 0; r < 4; ++r) { mrun[m][r] = -3.0e38f; lrun[m][r] = 0.f; }

  const int qg0 = qb * 128 + wid * 32;
  const int ktiles = 2 * qb + 2;

  for (int kt = 0; kt < ktiles; ++kt) {
    __syncthreads();
#pragma unroll
    for (int i = 0; i < 4; ++i) {
      const int lr = i * 16 + wid * 4;
      const int r  = lr + (lane >> 4);
      gload_lds16(Kb + ((long)b * S + kt * 64 + r) * (long)D + h * Dh + sw8(r, (lane & 15) * 8),
                  &Ks[lr][0]);
    }
#pragma unroll
    for (int i = 0; i < 4; ++i) {
      const int lr = i * 32 + wid * 8;
      const int r  = lr + (lane >> 3);
      gload_lds16(Vt + ((long)bh * Dh + r) * (long)S + kt * 64 + sw8(r, (lane & 7) * 8),
                  &Vs[lr][0]);
    }
    __syncthreads();

    const bool active = (kt * 64) <= (qg0 + 31);

    if (active) {
      f32x4_t sacc[2][4];
#pragma unroll
      for (int m = 0; m < 2; ++m)
#pragma unroll
        for (int n = 0; n < 4; ++n)
#pragma unroll
          for (int r = 0; r < 4; ++r) sacc[m][n][r] = 0.f;

#pragma unroll
      for (int kk = 0; kk < 4; ++kk) {
        bf16x8_t bk[4];
#pragma unroll
        for (int n = 0; n < 4; ++n) {
          const int krow = n * 16 + frow;
          bk[n] = *reinterpret_cast<const bf16x8_t*>(&Ks[krow][sw8(krow, kk * 32 + fk8)]);
        }
#pragma unroll
        for (int m = 0; m < 2; ++m)
#pragma unroll
          for (int n = 0; n < 4; ++n)
            sacc[m][n] = __builtin_amdgcn_mfma_f32_16x16x32_bf16(aq[m][kk], bk[n], sacc[m][n], 0, 0, 0);
      }

      float tmax[2][4];
#pragma unroll
      for (int m = 0; m < 2; ++m)
#pragma unroll
        for (int r = 0; r < 4; ++r) tmax[m][r] = -3.0e38f;

#pragma unroll
      for (int m = 0; m < 2; ++m)
#pragma unroll
        for (int n = 0; n < 4; ++n)
#pragma unroll
          for (int r = 0; r < 4; ++r) {
            const int qg = qg0 + m * 16 + orow + r;
            const int kg = kt * 64 + n * 16 + ocol;
            float v = sacc[m][n][r] * sm_scale + slope * (float)(kg - qg);
            v = (kg <= qg) ? v : -1.0e30f;
            sacc[m][n][r] = v;
            tmax[m][r] = fmaxf(tmax[m][r], v);
          }
#pragma unroll
      for (int m = 0; m < 2; ++m)
#pragma unroll
        for (int r = 0; r < 4; ++r) {
          float t = tmax[m][r];
          t = fmaxf(t, __shfl_xor(t, 1));
          t = fmaxf(t, __shfl_xor(t, 2));
          t = fmaxf(t, __shfl_xor(t, 4));
          t = fmaxf(t, __shfl_xor(t, 8));
          tmax[m][r] = t;
        }

      float tsum[2][4];
#pragma unroll
      for (int m = 0; m < 2; ++m)
#pragma unroll
        for (int r = 0; r < 4; ++r) {
          const float mnew = fmaxf(mrun[m][r], tmax[m][r]);
          const float alpha = __expf(mrun[m][r] - mnew);
          mrun[m][r] = mnew;
          lrun[m][r] *= alpha;
#pragma unroll
          for (int no = 0; no < 8; ++no) oacc[m][no][r] *= alpha;
          tsum[m][r] = 0.f;
        }
#pragma unroll
      for (int m = 0; m < 2; ++m)
#pragma unroll
        for (int n = 0; n < 4; ++n)
#pragma unroll
          for (int r = 0; r < 4; ++r) {
            const float p = __expf(sacc[m][n][r] - mrun[m][r]);
            tsum[m][r] += p;
            const int prow = wid * 32 + m * 16 + orow + r;
            Ps[prow][sw8(prow, n * 16 + ocol)] = f2bf(p);
          }
#pragma unroll
      for (int m = 0; m < 2; ++m)
#pragma unroll
        for (int r = 0; r < 4; ++r) {
          float t = tsum[m][r];
          t += __shfl_xor(t, 1);
          t += __shfl_xor(t, 2);
          t += __shfl_xor(t, 4);
          t += __shfl_xor(t, 8);
          lrun[m][r] += t;
        }
    }

    __syncthreads();

    if (active) {
#pragma unroll
      for (int kk = 0; kk < 2; ++kk) {
        bf16x8_t pa[2];
        const int prow0 = wid * 32 + frow;
        const int prow1 = wid * 32 + 16 + frow;
        pa[0] = *reinterpret_cast<const bf16x8_t*>(&Ps[prow0][sw8(prow0, kk * 32 + fk8)]);
        pa[1] = *reinterpret_cast<const bf16x8_t*>(&Ps[prow1][sw8(prow1, kk * 32 + fk8)]);
#pragma unroll
        for (int no = 0; no < 8; ++no) {
          const int vrow = no * 16 + frow;
          bf16x8_t bv = *reinterpret_cast<const bf16x8_t*>(&Vs[vrow][sw8(vrow, kk * 32 + fk8)]);
          oacc[0][no] = __builtin_amdgcn_mfma_f32_16x16x32_bf16(pa[0], bv, oacc[0][no], 0, 0, 0);
          oacc[1][no] = __builtin_amdgcn_mfma_f32_16x16x32_bf16(pa[1], bv, oacc[1][no], 0, 0, 0);
        }
      }
    }
  }

#pragma unroll
  for (int m = 0; m < 2; ++m)
#pragma unroll
    for (int r = 0; r < 4; ++r) {
      const float rl = 1.0f / lrun[m][r];
      const long trow = qrow0 + m * 16 + orow + r;
#pragma unroll
      for (int no = 0; no < 8; ++no)
        Out[trow * (long)D + h * Dh + no * 16 + ocol] = f2bf(oacc[m][no][r] * rl);
    }
}

// ---- launch --------------------------------------------------------------

extern "C" void kernel_launch(void* const* d_in, const int* in_sizes, int n_in,
                              void* d_out, int out_size, void* d_ws, size_t ws_size,
                              hipStream_t stream) {
  const float* hs   = (const float*)d_in[0];
  const float* qkvw = (const float*)d_in[1];
  const float* ow   = (const float*)d_in[2];

  const int D = 2048, B = 2, H = 16;
  const long TD = (long)in_sizes[0];   // T*D = 8388608
  const long DD = (long)in_sizes[2];   // D*D = 4194304
  const int T = (int)(TD / D);         // 4096
  const int S = T / B;                 // 2048
  const int Dh = D / H;                // 128
  const float sm_scale = 1.0f / sqrtf((float)Dh);

  u16* ws  = (u16*)d_ws;
  u16* hsb = ws;                  // TD    (later reused as attn)
  u16* wt  = ws + TD;             // 3*DD  (later reused as vt)
  u16* owt = wt + 3 * DD;         // DD
  u16* qkv = owt + DD;            // 3*TD  [Q | K | V]
  u16* vt   = wt;                 // TD    (overlay; wt dead after QKV GEMM)
  u16* attn = hsb;                // TD    (overlay; hsb dead after QKV GEMM)

  // 1) hidden -> bf16
  k_cast_bf16<<<dim3((unsigned)(TD / 1024)), 256, 0, stream>>>(hs, hsb, TD);
  // 2) qkv weights: cast + transpose to [3][E][D] (== fused Bt [6144][2048])
  k_transpose_cast<<<dim3(D / 32, D / 32, 3), 256, 0, stream>>>(qkvw, wt, D, D);
  // 3) o_proj weight: cast + transpose to [E][D]
  k_transpose_cast<<<dim3(D / 32, D / 32, 1), 256, 0, stream>>>(ow, owt, D, D);
  // 4) fused QKV projection: [4096 x 6144] = hsb @ wt^T (epilogue splits mats)
  k_gemm8<u16><<<dim3((3 * D) / 256, T / 256), 512, 0, stream>>>(
      hsb, wt, qkv, T, 3 * D, D, TD);
  // 5) V -> Vt[bh][Dh][S]
  k_transpose_v<<<dim3(S / 32, Dh / 32, B * H), 256, 0, stream>>>(
      qkv + 2 * TD, vt, S, D, Dh, H);
  // 6) attention
  k_attn<<<dim3(S / 128, B * H), 256, 0, stream>>>(
      qkv, qkv + TD, vt, attn, B, S, H, D, sm_scale);
  // 7) output projection -> f32 d_out
  k_gemm8<float><<<dim3(D / 256, T / 256), 512, 0, stream>>>(
      attn, owt, (float*)d_out, T, D, D, 0L);
}

// Round 5
// 312.169 us; speedup vs baseline: 1.5578x; 1.0662x over previous
//
#include <hip/hip_runtime.h>
#include <math.h>
#include <stdint.h>

typedef __bf16 bf16x8_t __attribute__((ext_vector_type(8)));
typedef float  f32x4_t  __attribute__((ext_vector_type(4)));
typedef unsigned short u16;

// ---- helpers -------------------------------------------------------------

__device__ __forceinline__ u16 f2bf(float f) {
  unsigned u = __float_as_uint(f);
  u += 0x7FFFu + ((u >> 16) & 1u);
  return (u16)(u >> 16);
}

__device__ __forceinline__ void gload_lds16(const u16* gsrc, u16* ldst) {
  // async global->LDS, 16B per lane; LDS dest = wave-uniform base + lane*16
  __builtin_amdgcn_global_load_lds(
      (__attribute__((address_space(1))) void*)(const_cast<u16*>(gsrc)),
      (__attribute__((address_space(3))) void*)(ldst),
      16, 0, 0);
}

// XOR bank-conflict swizzle: byte ^= ((row&7)<<4) == elem ^= ((row&7)<<3)
__device__ __forceinline__ int sw8(int row, int e) { return e ^ ((row & 7) << 3); }

__device__ __forceinline__ void store_out(float* C, long idx, float v) { C[idx] = v; }
__device__ __forceinline__ void store_out(u16* C, long idx, float v) { C[idx] = f2bf(v); }

__device__ __forceinline__ float alibi_slope(int h, int H) {
  int cp2 = 1, lg = 0;
  while (cp2 * 2 <= H) { cp2 *= 2; lg++; }
  if (h < cp2) {
    double e = exp2((double)-(lg - 3));
    return (float)exp2(-e * (double)(h + 1));
  } else {
    double e = exp2((double)-(lg + 1 - 3));
    return (float)exp2(-e * (double)(2 * (h - cp2) + 1));
  }
}

#define FENCE() asm volatile("" ::: "memory")
#define BARRIER() do { FENCE(); __builtin_amdgcn_s_barrier(); \
                       __builtin_amdgcn_sched_barrier(0); FENCE(); } while (0)
#define WAITLGKM() do { asm volatile("s_waitcnt lgkmcnt(0)" ::: "memory"); \
                        __builtin_amdgcn_sched_barrier(0); } while (0)

// ---- elementwise cast f32 -> bf16 ---------------------------------------

__global__ __launch_bounds__(256) void k_cast_bf16(const float* __restrict__ in,
                                                   u16* __restrict__ out, long n) {
  long i = ((long)blockIdx.x * 256 + threadIdx.x) * 4;
  if (i + 3 < n) {
    float4 v = *reinterpret_cast<const float4*>(in + i);
    ushort4 o;
    o.x = f2bf(v.x); o.y = f2bf(v.y); o.z = f2bf(v.z); o.w = f2bf(v.w);
    *reinterpret_cast<ushort4*>(out + i) = o;
  }
}

// ---- transpose + cast: out[z][c][r] = bf16(in[z][r][c]) ------------------

__global__ __launch_bounds__(256) void k_transpose_cast(const float* __restrict__ in,
                                                        u16* __restrict__ out,
                                                        int R, int C) {
  __shared__ float tile[32][33];
  const float* inz = in + (long)blockIdx.z * R * C;
  u16* outz = out + (long)blockIdx.z * R * C;
  const int tx = threadIdx.x & 31, ty = threadIdx.x >> 5;
  const int r0 = blockIdx.y * 32, c0 = blockIdx.x * 32;
#pragma unroll
  for (int i = 0; i < 4; ++i)
    tile[ty + i * 8][tx] = inz[(long)(r0 + ty + i * 8) * C + c0 + tx];
  __syncthreads();
#pragma unroll
  for (int i = 0; i < 4; ++i)
    outz[(long)(c0 + ty + i * 8) * R + r0 + tx] = f2bf(tile[tx][ty + i * 8]);
}

// ---- per-(b,h) transpose of V: [S,Dh slice of D] -> Vt[bh][Dh][S] --------

__global__ __launch_bounds__(256) void k_transpose_v(const u16* __restrict__ V,
                                                     u16* __restrict__ Vt,
                                                     int S, int D, int Dh, int H) {
  __shared__ u16 tile[32][33];
  const int bh = blockIdx.z, b = bh / H, h = bh % H;
  const int tx = threadIdx.x & 31, ty = threadIdx.x >> 5;
  const int s0 = blockIdx.x * 32, d0 = blockIdx.y * 32;
  const u16* vin = V + (long)b * S * D + (long)h * Dh;
#pragma unroll
  for (int i = 0; i < 4; ++i)
    tile[ty + i * 8][tx] = vin[(long)(s0 + ty + i * 8) * D + d0 + tx];
  __syncthreads();
  u16* vout = Vt + (long)bh * Dh * S;
#pragma unroll
  for (int i = 0; i < 4; ++i)
    vout[(long)(d0 + ty + i * 8) * S + s0 + tx] = tile[tx][ty + i * 8];
}

// ---- 256x256 8-phase bf16 GEMM (T1+T2+T3+T4+T5), bt pattern --------------
// C[M,N] = A[M,K] * Bt[N,K]^T. qs scales cols 0..2047 of the output (used
// to prescale Q by sm_scale*log2e for the log2-domain attention softmax).

__device__ __forceinline__ void stage16(const u16* __restrict__ g, long grow0, int K,
                                        int kt, int lr0, u16 (*lds)[64], int lane) {
  const int e = (lane & 7) * 8;
#pragma unroll
  for (int i = 0; i < 2; ++i) {
    const int r = lr0 + i * 8 + (lane >> 3);
    gload_lds16(g + (grow0 + r) * (long)K + kt + (e ^ ((r & 7) << 3)), &lds[lr0 + i * 8][0]);
  }
}

template <typename OUT_T>
__global__ __launch_bounds__(512, 2) void k_gemm8(const u16* __restrict__ A,
                                                  const u16* __restrict__ Bt,
                                                  OUT_T* __restrict__ Cb,
                                                  int M, int N, int K, long matStride,
                                                  float qs) {
  __shared__ u16 As[2][256][64];
  __shared__ u16 Bs[2][256][64];

  const int tid = threadIdx.x, wid = tid >> 6, lane = tid & 63;
  const int wr = wid >> 2, wc = wid & 3;
  const int frow = lane & 15, fk8 = (lane >> 4) * 8;
  const int orow = (lane >> 4) * 4, ocol = lane & 15;

  // T1: bijective XCD-aware swizzle
  const int nwg = gridDim.x * gridDim.y;
  const int orig = blockIdx.y * gridDim.x + blockIdx.x;
  const int q = nwg >> 3, rr = nwg & 7;
  const int xcd = orig & 7, sl = orig >> 3;
  const int wg = (xcd < rr ? xcd * (q + 1) : rr * (q + 1) + (xcd - rr) * q) + sl;
  const int by = wg / gridDim.x, bx = wg % gridDim.x;

  const long abase = (long)by * 256, bbase = (long)bx * 256;

  const int bg0 = (wid >> 1) * 64 + (wid & 1) * 16;
  const int ag0 = (wid >> 2) * 128 + (wid & 3) * 16;

  f32x4_t acc[8][4];
#pragma unroll
  for (int m = 0; m < 8; ++m)
#pragma unroll
    for (int n = 0; n < 4; ++n)
#pragma unroll
      for (int r = 0; r < 4; ++r) acc[m][n][r] = 0.f;

  const int nt = K >> 6;

  stage16(Bt, bbase, K, 0, bg0, Bs[0], lane);
  stage16(Bt, bbase, K, 0, bg0 + 32, Bs[0], lane);
  stage16(A, abase, K, 0, ag0, As[0], lane);
  stage16(A, abase, K, 0, ag0 + 64, As[0], lane);
  asm volatile("s_waitcnt vmcnt(2)" ::: "memory");
  BARRIER();

  bf16x8_t afr[4][2], bfr[4][2];
  int cur = 0;

  for (int t = 0; t < nt; ++t) {
    const int ktn = (t + 1) << 6;
    const bool hn = (t + 1 < nt);
    const int nb = cur ^ 1;

    // ---- phase 1
#pragma unroll
    for (int m = 0; m < 4; ++m) {
      const int r = wr * 128 + m * 16 + frow;
      afr[m][0] = *reinterpret_cast<const bf16x8_t*>(&As[cur][r][sw8(r, fk8)]);
      afr[m][1] = *reinterpret_cast<const bf16x8_t*>(&As[cur][r][sw8(r, 32 + fk8)]);
    }
#pragma unroll
    for (int n = 0; n < 2; ++n) {
      const int r = wc * 64 + n * 16 + frow;
      bfr[n][0] = *reinterpret_cast<const bf16x8_t*>(&Bs[cur][r][sw8(r, fk8)]);
      bfr[n][1] = *reinterpret_cast<const bf16x8_t*>(&Bs[cur][r][sw8(r, 32 + fk8)]);
    }
    if (hn) stage16(Bt, bbase, K, ktn, bg0, Bs[nb], lane);
    BARRIER();
    WAITLGKM();
    __builtin_amdgcn_s_setprio(1);
#pragma unroll
    for (int m = 0; m < 4; ++m)
#pragma unroll
      for (int n = 0; n < 2; ++n) {
        acc[m][n] = __builtin_amdgcn_mfma_f32_16x16x32_bf16(afr[m][0], bfr[n][0], acc[m][n], 0, 0, 0);
        acc[m][n] = __builtin_amdgcn_mfma_f32_16x16x32_bf16(afr[m][1], bfr[n][1], acc[m][n], 0, 0, 0);
      }
    __builtin_amdgcn_s_setprio(0);
    BARRIER();

    // ---- phase 2
#pragma unroll
    for (int n = 0; n < 2; ++n) {
      const int r = wc * 64 + 32 + n * 16 + frow;
      bfr[2 + n][0] = *reinterpret_cast<const bf16x8_t*>(&Bs[cur][r][sw8(r, fk8)]);
      bfr[2 + n][1] = *reinterpret_cast<const bf16x8_t*>(&Bs[cur][r][sw8(r, 32 + fk8)]);
    }
    if (hn) stage16(Bt, bbase, K, ktn, bg0 + 32, Bs[nb], lane);
    BARRIER();
    WAITLGKM();
    __builtin_amdgcn_s_setprio(1);
#pragma unroll
    for (int m = 0; m < 4; ++m)
#pragma unroll
      for (int n = 0; n < 2; ++n) {
        acc[m][2 + n] = __builtin_amdgcn_mfma_f32_16x16x32_bf16(afr[m][0], bfr[2 + n][0], acc[m][2 + n], 0, 0, 0);
        acc[m][2 + n] = __builtin_amdgcn_mfma_f32_16x16x32_bf16(afr[m][1], bfr[2 + n][1], acc[m][2 + n], 0, 0, 0);
      }
    __builtin_amdgcn_s_setprio(0);
    if (hn) asm volatile("s_waitcnt vmcnt(4)" ::: "memory");
    else    asm volatile("s_waitcnt vmcnt(0)" ::: "memory");
    BARRIER();

    // ---- phase 3
#pragma unroll
    for (int m = 0; m < 4; ++m) {
      const int r = wr * 128 + 64 + m * 16 + frow;
      afr[m][0] = *reinterpret_cast<const bf16x8_t*>(&As[cur][r][sw8(r, fk8)]);
      afr[m][1] = *reinterpret_cast<const bf16x8_t*>(&As[cur][r][sw8(r, 32 + fk8)]);
    }
    if (hn) stage16(A, abase, K, ktn, ag0, As[nb], lane);
    BARRIER();
    WAITLGKM();
    __builtin_amdgcn_s_setprio(1);
#pragma unroll
    for (int m = 0; m < 4; ++m)
#pragma unroll
      for (int n = 0; n < 2; ++n) {
        acc[4 + m][n] = __builtin_amdgcn_mfma_f32_16x16x32_bf16(afr[m][0], bfr[n][0], acc[4 + m][n], 0, 0, 0);
        acc[4 + m][n] = __builtin_amdgcn_mfma_f32_16x16x32_bf16(afr[m][1], bfr[n][1], acc[4 + m][n], 0, 0, 0);
      }
    __builtin_amdgcn_s_setprio(0);
    BARRIER();

    // ---- phase 4
    if (hn) stage16(A, abase, K, ktn, ag0 + 64, As[nb], lane);
    __builtin_amdgcn_s_setprio(1);
#pragma unroll
    for (int m = 0; m < 4; ++m)
#pragma unroll
      for (int n = 0; n < 2; ++n) {
        acc[4 + m][2 + n] = __builtin_amdgcn_mfma_f32_16x16x32_bf16(afr[m][0], bfr[2 + n][0], acc[4 + m][2 + n], 0, 0, 0);
        acc[4 + m][2 + n] = __builtin_amdgcn_mfma_f32_16x16x32_bf16(afr[m][1], bfr[2 + n][1], acc[4 + m][2 + n], 0, 0, 0);
      }
    __builtin_amdgcn_s_setprio(0);
    if (hn) asm volatile("s_waitcnt vmcnt(2)" ::: "memory");
    BARRIER();

    cur ^= 1;
  }

  // epilogue: C write; col -> (mat, e) split; Q-prescale on cols < 2048
#pragma unroll
  for (int m = 0; m < 8; ++m)
#pragma unroll
    for (int n = 0; n < 4; ++n)
#pragma unroll
      for (int r = 0; r < 4; ++r) {
        const long row = abase + wr * 128 + m * 16 + orow + r;
        const int col = (int)bbase + wc * 64 + n * 16 + ocol;
        const float sc = ((col >> 11) == 0) ? qs : 1.0f;
        const long idx = (long)(col >> 11) * matStride + row * 2048 + (col & 2047);
        store_out(Cb, idx, acc[m][n][r] * sc);
      }
}

// ---- flash attention, QBLK=64, log2-domain softmax -----------------------
// grid: (S/64, B*H) remapped for causal load balance. 4 waves x 16 q-rows.
// Q prescaled by sm_scale*log2e in the QKV GEMM; ALiBi row term cancels in
// softmax -> bias = slope*log2e*k (column-only). Standard per-tile rescale
// (defer-max removed for this A/B); mid-barrier between P-write and PV
// reinstated (round-4 suspect #1).

__global__ __launch_bounds__(256) void k_attn(const u16* __restrict__ Q,
                                              const u16* __restrict__ Kb,
                                              const u16* __restrict__ Vt,
                                              u16* __restrict__ Out,
                                              int B, int S, int H, int D,
                                              float log2e) {
  __shared__ u16 Ks[64][128];   // 16KB (swizzled)
  __shared__ u16 Vs[128][64];   // 16KB (swizzled)
  __shared__ u16 Ps[64][64];    //  8KB (swizzled, wave-private rows)

  const int tid = threadIdx.x, wid = tid >> 6, lane = tid & 63;

  // causal work pairing: qb0 and nq-1-qb0 pair to constant work
  const int nq = gridDim.x, nbh = gridDim.y;
  const int lin = blockIdx.x + nq * blockIdx.y;
  const int qb0 = lin / nbh;
  const int bh  = lin % nbh;
  const int qb  = (qb0 < nq / 2) ? qb0 : (nq + nq / 2 - 1 - qb0);

  const int b = bh / H, h = bh % H;
  const int Dh = D / H;  // 128

  const float slope2 = alibi_slope(h, H) * log2e;
  const long qrow0 = (long)b * S + qb * 64 + wid * 16;

  const int frow = lane & 15;
  const int fk8  = (lane >> 4) * 8;
  const int orow = (lane >> 4) * 4;
  const int ocol = lane & 15;

  // Q fragments (already scaled by sm_scale*log2e): 1 m-frag x 4 k-steps
  bf16x8_t aq[4];
#pragma unroll
  for (int kk = 0; kk < 4; ++kk)
    aq[kk] = *reinterpret_cast<const bf16x8_t*>(
        Q + (qrow0 + frow) * (long)D + h * Dh + kk * 32 + fk8);

  // column-bias partial: slope2 * (n*16 + ocol)
  float cw[4];
#pragma unroll
  for (int n = 0; n < 4; ++n) cw[n] = slope2 * (float)(n * 16 + ocol);

  f32x4_t oacc[8];
#pragma unroll
  for (int no = 0; no < 8; ++no)
#pragma unroll
    for (int r = 0; r < 4; ++r) oacc[no][r] = 0.f;

  float Mrun[4], lrun[4];
#pragma unroll
  for (int r = 0; r < 4; ++r) { Mrun[r] = -3.0e38f; lrun[r] = 0.f; }

  const u16* kbase = Kb + (long)b * S * D + h * Dh;
  const u16* vbase = Vt + (long)bh * Dh * S;

  const int ntile = qb + 1;

  for (int kt = 0; kt < ntile; ++kt) {
    __syncthreads();
    // stage K tile (64 x 128), swizzled source
#pragma unroll
    for (int i = 0; i < 4; ++i) {
      const int lr = i * 16 + wid * 4;
      const int r  = lr + (lane >> 4);
      gload_lds16(kbase + ((long)kt * 64 + r) * (long)D + sw8(r, (lane & 15) * 8), &Ks[lr][0]);
    }
    // stage Vt tile (128 x 64), swizzled source
#pragma unroll
    for (int i = 0; i < 4; ++i) {
      const int lr = i * 32 + wid * 8;
      const int r  = lr + (lane >> 3);
      gload_lds16(vbase + (long)r * S + kt * 64 + sw8(r, (lane & 7) * 8), &Vs[lr][0]);
    }
    __syncthreads();

    // S = Q K^T (16 x 64 per wave), log2 domain
    f32x4_t sacc[4];
#pragma unroll
    for (int n = 0; n < 4; ++n)
#pragma unroll
      for (int r = 0; r < 4; ++r) sacc[n][r] = 0.f;

#pragma unroll
    for (int kk = 0; kk < 4; ++kk) {
      bf16x8_t bk[4];
#pragma unroll
      for (int n = 0; n < 4; ++n) {
        const int krow = n * 16 + frow;
        bk[n] = *reinterpret_cast<const bf16x8_t*>(&Ks[krow][sw8(krow, kk * 32 + fk8)]);
      }
#pragma unroll
      for (int n = 0; n < 4; ++n)
        sacc[n] = __builtin_amdgcn_mfma_f32_16x16x32_bf16(aq[kk], bk[n], sacc[n], 0, 0, 0);
    }

    // column bias + (diagonal tile only) causal mask + row max
    const float tb = slope2 * (float)(kt << 6);
    float cbn[4];
#pragma unroll
    for (int n = 0; n < 4; ++n) cbn[n] = tb + cw[n];

    float tmax[4];
#pragma unroll
    for (int r = 0; r < 4; ++r) tmax[r] = -3.0e38f;

    if (kt == qb) {  // diagonal tile: mask k > q (indices qb-independent)
#pragma unroll
      for (int n = 0; n < 4; ++n)
#pragma unroll
        for (int r = 0; r < 4; ++r) {
          float v = sacc[n][r] + cbn[n];
          v = (n * 16 + ocol <= wid * 16 + orow + r) ? v : -1.0e30f;
          sacc[n][r] = v;
          tmax[r] = fmaxf(tmax[r], v);
        }
    } else {
#pragma unroll
      for (int n = 0; n < 4; ++n)
#pragma unroll
        for (int r = 0; r < 4; ++r) {
          const float v = sacc[n][r] + cbn[n];
          sacc[n][r] = v;
          tmax[r] = fmaxf(tmax[r], v);
        }
    }
#pragma unroll
    for (int r = 0; r < 4; ++r) {
      float t = tmax[r];
      t = fmaxf(t, __shfl_xor(t, 1));
      t = fmaxf(t, __shfl_xor(t, 2));
      t = fmaxf(t, __shfl_xor(t, 4));
      t = fmaxf(t, __shfl_xor(t, 8));
      tmax[r] = t;
    }

    // standard online softmax: rescale every tile
#pragma unroll
    for (int r = 0; r < 4; ++r) {
      const float mnew = fmaxf(Mrun[r], tmax[r]);
      const float alpha = exp2f(Mrun[r] - mnew);
      Mrun[r] = mnew;
      lrun[r] *= alpha;
#pragma unroll
      for (int no = 0; no < 8; ++no) oacc[no][r] *= alpha;
    }

    float tsum[4];
#pragma unroll
    for (int r = 0; r < 4; ++r) tsum[r] = 0.f;
#pragma unroll
    for (int n = 0; n < 4; ++n)
#pragma unroll
      for (int r = 0; r < 4; ++r) {
        const float p = exp2f(sacc[n][r] - Mrun[r]);
        tsum[r] += p;
        const int prow = wid * 16 + orow + r;
        Ps[prow][sw8(prow, n * 16 + ocol)] = f2bf(p);
      }
#pragma unroll
    for (int r = 0; r < 4; ++r) {
      float t = tsum[r];
      t += __shfl_xor(t, 1);
      t += __shfl_xor(t, 2);
      t += __shfl_xor(t, 4);
      t += __shfl_xor(t, 8);
      lrun[r] += t;
    }

    __syncthreads();  // P visible before PV (round-4 suspect #1 reinstated)

    // O += P V
#pragma unroll
    for (int kk = 0; kk < 2; ++kk) {
      const int prow = wid * 16 + frow;
      bf16x8_t pa = *reinterpret_cast<const bf16x8_t*>(&Ps[prow][sw8(prow, kk * 32 + fk8)]);
#pragma unroll
      for (int no = 0; no < 8; ++no) {
        const int vrow = no * 16 + frow;
        bf16x8_t bv = *reinterpret_cast<const bf16x8_t*>(&Vs[vrow][sw8(vrow, kk * 32 + fk8)]);
        oacc[no] = __builtin_amdgcn_mfma_f32_16x16x32_bf16(pa, bv, oacc[no], 0, 0, 0);
      }
    }
  }

  // epilogue
#pragma unroll
  for (int r = 0; r < 4; ++r) {
    const float rl = 1.0f / lrun[r];
    const long trow = qrow0 + orow + r;
#pragma unroll
    for (int no = 0; no < 8; ++no)
      Out[trow * (long)D + h * Dh + no * 16 + ocol] = f2bf(oacc[no][r] * rl);
  }
}

// ---- launch --------------------------------------------------------------

extern "C" void kernel_launch(void* const* d_in, const int* in_sizes, int n_in,
                              void* d_out, int out_size, void* d_ws, size_t ws_size,
                              hipStream_t stream) {
  const float* hs   = (const float*)d_in[0];
  const float* qkvw = (const float*)d_in[1];
  const float* ow   = (const float*)d_in[2];

  const int D = 2048, B = 2, H = 16;
  const long TD = (long)in_sizes[0];   // T*D = 8388608
  const long DD = (long)in_sizes[2];   // D*D = 4194304
  const int T = (int)(TD / D);         // 4096
  const int S = T / B;                 // 2048
  const int Dh = D / H;                // 128
  const float log2e = 1.44269504f;
  const float qs = (1.0f / sqrtf((float)Dh)) * log2e;  // Q prescale

  u16* ws  = (u16*)d_ws;
  u16* hsb = ws;                  // TD    (later reused as attn)
  u16* wt  = ws + TD;             // 3*DD  (later reused as vt)
  u16* owt = wt + 3 * DD;         // DD
  u16* qkv = owt + DD;            // 3*TD  [Q | K | V]
  u16* vt   = wt;                 // TD    (overlay; wt dead after QKV GEMM)
  u16* attn = hsb;                // TD    (overlay; hsb dead after QKV GEMM)

  // 1) hidden -> bf16
  k_cast_bf16<<<dim3((unsigned)(TD / 1024)), 256, 0, stream>>>(hs, hsb, TD);
  // 2) qkv weights: cast + transpose to [3][E][D] (== fused Bt [6144][2048])
  k_transpose_cast<<<dim3(D / 32, D / 32, 3), 256, 0, stream>>>(qkvw, wt, D, D);
  // 3) o_proj weight: cast + transpose to [E][D]
  k_transpose_cast<<<dim3(D / 32, D / 32, 1), 256, 0, stream>>>(ow, owt, D, D);
  // 4) fused QKV projection (Q prescaled by sm_scale*log2e in epilogue)
  k_gemm8<u16><<<dim3((3 * D) / 256, T / 256), 512, 0, stream>>>(
      hsb, wt, qkv, T, 3 * D, D, TD, qs);
  // 5) V -> Vt[bh][Dh][S]
  k_transpose_v<<<dim3(S / 32, Dh / 32, B * H), 256, 0, stream>>>(
      qkv + 2 * TD, vt, S, D, Dh, H);
  // 6) attention (QBLK=64, log2 domain)
  k_attn<<<dim3(S / 64, B * H), 256, 0, stream>>>(
      qkv, qkv + TD, vt, attn, B, S, H, D, log2e);
  // 7) output projection -> f32 d_out
  k_gemm8<float><<<dim3(D / 256, T / 256), 512, 0, stream>>>(
      attn, owt, (float*)d_out, T, D, D, 0L, 1.0f);
}

// Round 6
// 292.396 us; speedup vs baseline: 1.6632x; 1.0676x over previous
//
#include <hip/hip_runtime.h>
#include <math.h>
#include <stdint.h>

typedef __bf16 bf16x8_t __attribute__((ext_vector_type(8)));
typedef float  f32x4_t  __attribute__((ext_vector_type(4)));
typedef unsigned short u16;

// ---- helpers -------------------------------------------------------------

__device__ __forceinline__ u16 f2bf(float f) {
  unsigned u = __float_as_uint(f);
  u += 0x7FFFu + ((u >> 16) & 1u);
  return (u16)(u >> 16);
}

__device__ __forceinline__ void gload_lds16(const u16* gsrc, u16* ldst) {
  // async global->LDS, 16B per lane; LDS dest = wave-uniform base + lane*16
  __builtin_amdgcn_global_load_lds(
      (__attribute__((address_space(1))) void*)(const_cast<u16*>(gsrc)),
      (__attribute__((address_space(3))) void*)(ldst),
      16, 0, 0);
}

// XOR bank-conflict swizzle: byte ^= ((row&7)<<4) == elem ^= ((row&7)<<3)
__device__ __forceinline__ int sw8(int row, int e) { return e ^ ((row & 7) << 3); }

__device__ __forceinline__ void store_out(float* C, long idx, float v) { C[idx] = v; }
__device__ __forceinline__ void store_out(u16* C, long idx, float v) { C[idx] = f2bf(v); }

__device__ __forceinline__ float alibi_slope(int h, int H) {
  int cp2 = 1, lg = 0;
  while (cp2 * 2 <= H) { cp2 *= 2; lg++; }
  if (h < cp2) {
    double e = exp2((double)-(lg - 3));
    return (float)exp2(-e * (double)(h + 1));
  } else {
    double e = exp2((double)-(lg + 1 - 3));
    return (float)exp2(-e * (double)(2 * (h - cp2) + 1));
  }
}

#define FENCE() asm volatile("" ::: "memory")
#define BARRIER() do { FENCE(); __builtin_amdgcn_s_barrier(); \
                       __builtin_amdgcn_sched_barrier(0); FENCE(); } while (0)
#define WAITLGKM() do { asm volatile("s_waitcnt lgkmcnt(0)" ::: "memory"); \
                        __builtin_amdgcn_sched_barrier(0); } while (0)

// ---- elementwise cast f32 -> bf16 ---------------------------------------

__global__ __launch_bounds__(256) void k_cast_bf16(const float* __restrict__ in,
                                                   u16* __restrict__ out, long n) {
  long i = ((long)blockIdx.x * 256 + threadIdx.x) * 4;
  if (i + 3 < n) {
    float4 v = *reinterpret_cast<const float4*>(in + i);
    ushort4 o;
    o.x = f2bf(v.x); o.y = f2bf(v.y); o.z = f2bf(v.z); o.w = f2bf(v.w);
    *reinterpret_cast<ushort4*>(out + i) = o;
  }
}

// ---- transpose + cast: out[z][c][r] = bf16(in[z][r][c]) ------------------

__global__ __launch_bounds__(256) void k_transpose_cast(const float* __restrict__ in,
                                                        u16* __restrict__ out,
                                                        int R, int C) {
  __shared__ float tile[32][33];
  const float* inz = in + (long)blockIdx.z * R * C;
  u16* outz = out + (long)blockIdx.z * R * C;
  const int tx = threadIdx.x & 31, ty = threadIdx.x >> 5;
  const int r0 = blockIdx.y * 32, c0 = blockIdx.x * 32;
#pragma unroll
  for (int i = 0; i < 4; ++i)
    tile[ty + i * 8][tx] = inz[(long)(r0 + ty + i * 8) * C + c0 + tx];
  __syncthreads();
#pragma unroll
  for (int i = 0; i < 4; ++i)
    outz[(long)(c0 + ty + i * 8) * R + r0 + tx] = f2bf(tile[tx][ty + i * 8]);
}

// ---- per-(b,h) transpose of V: [S,Dh slice of D] -> Vt[bh][Dh][S] --------

__global__ __launch_bounds__(256) void k_transpose_v(const u16* __restrict__ V,
                                                     u16* __restrict__ Vt,
                                                     int S, int D, int Dh, int H) {
  __shared__ u16 tile[32][33];
  const int bh = blockIdx.z, b = bh / H, h = bh % H;
  const int tx = threadIdx.x & 31, ty = threadIdx.x >> 5;
  const int s0 = blockIdx.x * 32, d0 = blockIdx.y * 32;
  const u16* vin = V + (long)b * S * D + (long)h * Dh;
#pragma unroll
  for (int i = 0; i < 4; ++i)
    tile[ty + i * 8][tx] = vin[(long)(s0 + ty + i * 8) * D + d0 + tx];
  __syncthreads();
  u16* vout = Vt + (long)bh * Dh * S;
#pragma unroll
  for (int i = 0; i < 4; ++i)
    vout[(long)(d0 + ty + i * 8) * S + s0 + tx] = tile[tx][ty + i * 8];
}

// ---- staging helpers (linear LDS dest + inverse-swizzled global source) --

__device__ __forceinline__ void stage16(const u16* __restrict__ g, long grow0, int K,
                                        int kt, int lr0, u16 (*lds)[64], int lane) {
  const int e = (lane & 7) * 8;
#pragma unroll
  for (int i = 0; i < 2; ++i) {
    const int r = lr0 + i * 8 + (lane >> 3);
    gload_lds16(g + (grow0 + r) * (long)K + kt + (e ^ ((r & 7) << 3)), &lds[lr0 + i * 8][0]);
  }
}

__device__ __forceinline__ void stage8(const u16* __restrict__ g, long grow0, int K,
                                       int kt, int lr0, u16 (*lds)[64], int lane) {
  const int e = (lane & 7) * 8;
  const int r = lr0 + (lane >> 3);
  gload_lds16(g + (grow0 + r) * (long)K + kt + (e ^ ((r & 7) << 3)), &lds[lr0][0]);
}

// ---- 256x256 8-phase bf16 GEMM (T1+T2+T3+T4+T5), bt pattern --------------
// C[M,N] = A[M,K] * Bt[N,K]^T. qs scales cols 0..2047 of the output.

template <typename OUT_T>
__global__ __launch_bounds__(512, 2) void k_gemm8(const u16* __restrict__ A,
                                                  const u16* __restrict__ Bt,
                                                  OUT_T* __restrict__ Cb,
                                                  int M, int N, int K, long matStride,
                                                  float qs) {
  __shared__ u16 As[2][256][64];
  __shared__ u16 Bs[2][256][64];

  const int tid = threadIdx.x, wid = tid >> 6, lane = tid & 63;
  const int wr = wid >> 2, wc = wid & 3;
  const int frow = lane & 15, fk8 = (lane >> 4) * 8;
  const int orow = (lane >> 4) * 4, ocol = lane & 15;

  const int nwg = gridDim.x * gridDim.y;
  const int orig = blockIdx.y * gridDim.x + blockIdx.x;
  const int q = nwg >> 3, rr = nwg & 7;
  const int xcd = orig & 7, sl = orig >> 3;
  const int wg = (xcd < rr ? xcd * (q + 1) : rr * (q + 1) + (xcd - rr) * q) + sl;
  const int by = wg / gridDim.x, bx = wg % gridDim.x;

  const long abase = (long)by * 256, bbase = (long)bx * 256;

  const int bg0 = (wid >> 1) * 64 + (wid & 1) * 16;
  const int ag0 = (wid >> 2) * 128 + (wid & 3) * 16;

  f32x4_t acc[8][4];
#pragma unroll
  for (int m = 0; m < 8; ++m)
#pragma unroll
    for (int n = 0; n < 4; ++n)
#pragma unroll
      for (int r = 0; r < 4; ++r) acc[m][n][r] = 0.f;

  const int nt = K >> 6;

  stage16(Bt, bbase, K, 0, bg0, Bs[0], lane);
  stage16(Bt, bbase, K, 0, bg0 + 32, Bs[0], lane);
  stage16(A, abase, K, 0, ag0, As[0], lane);
  stage16(A, abase, K, 0, ag0 + 64, As[0], lane);
  asm volatile("s_waitcnt vmcnt(2)" ::: "memory");
  BARRIER();

  bf16x8_t afr[4][2], bfr[4][2];
  int cur = 0;

  for (int t = 0; t < nt; ++t) {
    const int ktn = (t + 1) << 6;
    const bool hn = (t + 1 < nt);
    const int nb = cur ^ 1;

    // ---- phase 1
#pragma unroll
    for (int m = 0; m < 4; ++m) {
      const int r = wr * 128 + m * 16 + frow;
      afr[m][0] = *reinterpret_cast<const bf16x8_t*>(&As[cur][r][sw8(r, fk8)]);
      afr[m][1] = *reinterpret_cast<const bf16x8_t*>(&As[cur][r][sw8(r, 32 + fk8)]);
    }
#pragma unroll
    for (int n = 0; n < 2; ++n) {
      const int r = wc * 64 + n * 16 + frow;
      bfr[n][0] = *reinterpret_cast<const bf16x8_t*>(&Bs[cur][r][sw8(r, fk8)]);
      bfr[n][1] = *reinterpret_cast<const bf16x8_t*>(&Bs[cur][r][sw8(r, 32 + fk8)]);
    }
    if (hn) stage16(Bt, bbase, K, ktn, bg0, Bs[nb], lane);
    BARRIER();
    WAITLGKM();
    __builtin_amdgcn_s_setprio(1);
#pragma unroll
    for (int m = 0; m < 4; ++m)
#pragma unroll
      for (int n = 0; n < 2; ++n) {
        acc[m][n] = __builtin_amdgcn_mfma_f32_16x16x32_bf16(afr[m][0], bfr[n][0], acc[m][n], 0, 0, 0);
        acc[m][n] = __builtin_amdgcn_mfma_f32_16x16x32_bf16(afr[m][1], bfr[n][1], acc[m][n], 0, 0, 0);
      }
    __builtin_amdgcn_s_setprio(0);
    BARRIER();

    // ---- phase 2
#pragma unroll
    for (int n = 0; n < 2; ++n) {
      const int r = wc * 64 + 32 + n * 16 + frow;
      bfr[2 + n][0] = *reinterpret_cast<const bf16x8_t*>(&Bs[cur][r][sw8(r, fk8)]);
      bfr[2 + n][1] = *reinterpret_cast<const bf16x8_t*>(&Bs[cur][r][sw8(r, 32 + fk8)]);
    }
    if (hn) stage16(Bt, bbase, K, ktn, bg0 + 32, Bs[nb], lane);
    BARRIER();
    WAITLGKM();
    __builtin_amdgcn_s_setprio(1);
#pragma unroll
    for (int m = 0; m < 4; ++m)
#pragma unroll
      for (int n = 0; n < 2; ++n) {
        acc[m][2 + n] = __builtin_amdgcn_mfma_f32_16x16x32_bf16(afr[m][0], bfr[2 + n][0], acc[m][2 + n], 0, 0, 0);
        acc[m][2 + n] = __builtin_amdgcn_mfma_f32_16x16x32_bf16(afr[m][1], bfr[2 + n][1], acc[m][2 + n], 0, 0, 0);
      }
    __builtin_amdgcn_s_setprio(0);
    if (hn) asm volatile("s_waitcnt vmcnt(4)" ::: "memory");
    else    asm volatile("s_waitcnt vmcnt(0)" ::: "memory");
    BARRIER();

    // ---- phase 3
#pragma unroll
    for (int m = 0; m < 4; ++m) {
      const int r = wr * 128 + 64 + m * 16 + frow;
      afr[m][0] = *reinterpret_cast<const bf16x8_t*>(&As[cur][r][sw8(r, fk8)]);
      afr[m][1] = *reinterpret_cast<const bf16x8_t*>(&As[cur][r][sw8(r, 32 + fk8)]);
    }
    if (hn) stage16(A, abase, K, ktn, ag0, As[nb], lane);
    BARRIER();
    WAITLGKM();
    __builtin_amdgcn_s_setprio(1);
#pragma unroll
    for (int m = 0; m < 4; ++m)
#pragma unroll
      for (int n = 0; n < 2; ++n) {
        acc[4 + m][n] = __builtin_amdgcn_mfma_f32_16x16x32_bf16(afr[m][0], bfr[n][0], acc[4 + m][n], 0, 0, 0);
        acc[4 + m][n] = __builtin_amdgcn_mfma_f32_16x16x32_bf16(afr[m][1], bfr[n][1], acc[4 + m][n], 0, 0, 0);
      }
    __builtin_amdgcn_s_setprio(0);
    BARRIER();

    // ---- phase 4
    if (hn) stage16(A, abase, K, ktn, ag0 + 64, As[nb], lane);
    __builtin_amdgcn_s_setprio(1);
#pragma unroll
    for (int m = 0; m < 4; ++m)
#pragma unroll
      for (int n = 0; n < 2; ++n) {
        acc[4 + m][2 + n] = __builtin_amdgcn_mfma_f32_16x16x32_bf16(afr[m][0], bfr[2 + n][0], acc[4 + m][2 + n], 0, 0, 0);
        acc[4 + m][2 + n] = __builtin_amdgcn_mfma_f32_16x16x32_bf16(afr[m][1], bfr[2 + n][1], acc[4 + m][2 + n], 0, 0, 0);
      }
    __builtin_amdgcn_s_setprio(0);
    if (hn) asm volatile("s_waitcnt vmcnt(2)" ::: "memory");
    BARRIER();

    cur ^= 1;
  }

#pragma unroll
  for (int m = 0; m < 8; ++m)
#pragma unroll
    for (int n = 0; n < 4; ++n)
#pragma unroll
      for (int r = 0; r < 4; ++r) {
        const long row = abase + wr * 128 + m * 16 + orow + r;
        const int col = (int)bbase + wc * 64 + n * 16 + ocol;
        const float sc = ((col >> 11) == 0) ? qs : 1.0f;
        const long idx = (long)(col >> 11) * matStride + row * 2048 + (col & 2047);
        store_out(Cb, idx, acc[m][n][r] * sc);
      }
}

// ---- 128x256 2-phase bf16 GEMM (grid-fill variant) -----------------------
// Same bt pattern; BM=128, BN=256, BK=64. 8 waves as 2M x 4N (wave 64x64,
// acc[4][4]). LDS 96 KiB double-buffered, swizzled. Per K-tile: ph1 reads
// all B-frags + A rows {0-31,64-95}, stages next-B (4 loads), vmcnt(4);
// ph2 reads A rows {32-63,96-127}, stages next-A (2 loads), vmcnt(1) —
// last-staged chunk (A2) is the last-read chunk of the next tile.

template <typename OUT_T>
__global__ __launch_bounds__(512, 2) void k_gemm2(const u16* __restrict__ A,
                                                  const u16* __restrict__ Bt,
                                                  OUT_T* __restrict__ Cb,
                                                  int M, int N, int K, long matStride,
                                                  float qs) {
  __shared__ u16 As[2][128][64];   // 32KB
  __shared__ u16 Bs[2][256][64];   // 64KB

  const int tid = threadIdx.x, wid = tid >> 6, lane = tid & 63;
  const int wr = wid >> 2, wc = wid & 3;     // 2M x 4N waves, wave tile 64x64
  const int frow = lane & 15, fk8 = (lane >> 4) * 8;
  const int orow = (lane >> 4) * 4, ocol = lane & 15;

  const int nwg = gridDim.x * gridDim.y;
  const int orig = blockIdx.y * gridDim.x + blockIdx.x;
  const int q = nwg >> 3, rr = nwg & 7;
  const int xcd = orig & 7, sl = orig >> 3;
  const int wg = (xcd < rr ? xcd * (q + 1) : rr * (q + 1) + (xcd - rr) * q) + sl;
  const int by = wg / gridDim.x, bx = wg % gridDim.x;

  const long abase = (long)by * 128, bbase = (long)bx * 256;

  const int bg0 = (wid >> 1) * 64 + (wid & 1) * 16;       // B: 16 rows/wave/call
  const int ag0 = ((wid & 1) << 6) + ((wid >> 1) << 3);   // A: 8 rows/wave/call
                                                          //   call1: {0-31,64-95}
  f32x4_t acc[4][4];
#pragma unroll
  for (int m = 0; m < 4; ++m)
#pragma unroll
    for (int n = 0; n < 4; ++n)
#pragma unroll
      for (int r = 0; r < 4; ++r) acc[m][n][r] = 0.f;

  const int nt = K >> 6;

  // prologue: B1(2) B2(2) A1(1) A2(1); leave A2 in flight (steady-state entry)
  stage16(Bt, bbase, K, 0, bg0, Bs[0], lane);
  stage16(Bt, bbase, K, 0, bg0 + 32, Bs[0], lane);
  stage8 (A,  abase, K, 0, ag0, As[0], lane);
  stage8 (A,  abase, K, 0, ag0 + 32, As[0], lane);
  asm volatile("s_waitcnt vmcnt(1)" ::: "memory");
  BARRIER();

  bf16x8_t bfr[4][2], afr[2][2];
  int cur = 0;

  for (int t = 0; t < nt; ++t) {
    const int ktn = (t + 1) << 6;
    const bool hn = (t + 1 < nt);
    const int nb = cur ^ 1;

    // ---- phase 1: all B-frags + A m0-1; MFMA acc[0..1][*]
#pragma unroll
    for (int n = 0; n < 4; ++n) {
      const int r = wc * 64 + n * 16 + frow;
      bfr[n][0] = *reinterpret_cast<const bf16x8_t*>(&Bs[cur][r][sw8(r, fk8)]);
      bfr[n][1] = *reinterpret_cast<const bf16x8_t*>(&Bs[cur][r][sw8(r, 32 + fk8)]);
    }
#pragma unroll
    for (int m = 0; m < 2; ++m) {
      const int r = wr * 64 + m * 16 + frow;
      afr[m][0] = *reinterpret_cast<const bf16x8_t*>(&As[cur][r][sw8(r, fk8)]);
      afr[m][1] = *reinterpret_cast<const bf16x8_t*>(&As[cur][r][sw8(r, 32 + fk8)]);
    }
    if (hn) {
      stage16(Bt, bbase, K, ktn, bg0, Bs[nb], lane);
      stage16(Bt, bbase, K, ktn, bg0 + 32, Bs[nb], lane);
    }
    BARRIER();
    WAITLGKM();
    __builtin_amdgcn_s_setprio(1);
#pragma unroll
    for (int m = 0; m < 2; ++m)
#pragma unroll
      for (int n = 0; n < 4; ++n) {
        acc[m][n] = __builtin_amdgcn_mfma_f32_16x16x32_bf16(afr[m][0], bfr[n][0], acc[m][n], 0, 0, 0);
        acc[m][n] = __builtin_amdgcn_mfma_f32_16x16x32_bf16(afr[m][1], bfr[n][1], acc[m][n], 0, 0, 0);
      }
    __builtin_amdgcn_s_setprio(0);
    // drain A2(t) before ph2 reads it; outstanding else: 4 B-loads of t+1
    if (hn) asm volatile("s_waitcnt vmcnt(4)" ::: "memory");
    else    asm volatile("s_waitcnt vmcnt(0)" ::: "memory");
    BARRIER();

    // ---- phase 2: A m2-3; MFMA acc[2..3][*]
#pragma unroll
    for (int m = 0; m < 2; ++m) {
      const int r = wr * 64 + 32 + m * 16 + frow;
      afr[m][0] = *reinterpret_cast<const bf16x8_t*>(&As[cur][r][sw8(r, fk8)]);
      afr[m][1] = *reinterpret_cast<const bf16x8_t*>(&As[cur][r][sw8(r, 32 + fk8)]);
    }
    if (hn) {
      stage8(A, abase, K, ktn, ag0, As[nb], lane);
      stage8(A, abase, K, ktn, ag0 + 32, As[nb], lane);
    }
    BARRIER();
    WAITLGKM();
    __builtin_amdgcn_s_setprio(1);
#pragma unroll
    for (int m = 0; m < 2; ++m)
#pragma unroll
      for (int n = 0; n < 4; ++n) {
        acc[2 + m][n] = __builtin_amdgcn_mfma_f32_16x16x32_bf16(afr[m][0], bfr[n][0], acc[2 + m][n], 0, 0, 0);
        acc[2 + m][n] = __builtin_amdgcn_mfma_f32_16x16x32_bf16(afr[m][1], bfr[n][1], acc[2 + m][n], 0, 0, 0);
      }
    __builtin_amdgcn_s_setprio(0);
    // drain B1,B2,A1(t+1); leave A2(t+1) in flight
    if (hn) asm volatile("s_waitcnt vmcnt(1)" ::: "memory");
    BARRIER();

    cur ^= 1;
  }

#pragma unroll
  for (int m = 0; m < 4; ++m)
#pragma unroll
    for (int n = 0; n < 4; ++n)
#pragma unroll
      for (int r = 0; r < 4; ++r) {
        const long row = abase + wr * 64 + m * 16 + orow + r;
        const int col = (int)bbase + wc * 64 + n * 16 + ocol;
        const float sc = ((col >> 11) == 0) ? qs : 1.0f;
        const long idx = (long)(col >> 11) * matStride + row * 2048 + (col & 2047);
        store_out(Cb, idx, acc[m][n][r] * sc);
      }
}

// ---- flash attention, QBLK=64, log2-domain softmax (proven in R5) --------

__global__ __launch_bounds__(256) void k_attn(const u16* __restrict__ Q,
                                              const u16* __restrict__ Kb,
                                              const u16* __restrict__ Vt,
                                              u16* __restrict__ Out,
                                              int B, int S, int H, int D,
                                              float log2e) {
  __shared__ u16 Ks[64][128];
  __shared__ u16 Vs[128][64];
  __shared__ u16 Ps[64][64];

  const int tid = threadIdx.x, wid = tid >> 6, lane = tid & 63;

  const int nq = gridDim.x, nbh = gridDim.y;
  const int lin = blockIdx.x + nq * blockIdx.y;
  const int qb0 = lin / nbh;
  const int bh  = lin % nbh;
  const int qb  = (qb0 < nq / 2) ? qb0 : (nq + nq / 2 - 1 - qb0);

  const int b = bh / H, h = bh % H;
  const int Dh = D / H;

  const float slope2 = alibi_slope(h, H) * log2e;
  const long qrow0 = (long)b * S + qb * 64 + wid * 16;

  const int frow = lane & 15;
  const int fk8  = (lane >> 4) * 8;
  const int orow = (lane >> 4) * 4;
  const int ocol = lane & 15;

  bf16x8_t aq[4];
#pragma unroll
  for (int kk = 0; kk < 4; ++kk)
    aq[kk] = *reinterpret_cast<const bf16x8_t*>(
        Q + (qrow0 + frow) * (long)D + h * Dh + kk * 32 + fk8);

  float cw[4];
#pragma unroll
  for (int n = 0; n < 4; ++n) cw[n] = slope2 * (float)(n * 16 + ocol);

  f32x4_t oacc[8];
#pragma unroll
  for (int no = 0; no < 8; ++no)
#pragma unroll
    for (int r = 0; r < 4; ++r) oacc[no][r] = 0.f;

  float Mrun[4], lrun[4];
#pragma unroll
  for (int r = 0; r < 4; ++r) { Mrun[r] = -3.0e38f; lrun[r] = 0.f; }

  const u16* kbase = Kb + (long)b * S * D + h * Dh;
  const u16* vbase = Vt + (long)bh * Dh * S;

  const int ntile = qb + 1;

  for (int kt = 0; kt < ntile; ++kt) {
    __syncthreads();
#pragma unroll
    for (int i = 0; i < 4; ++i) {
      const int lr = i * 16 + wid * 4;
      const int r  = lr + (lane >> 4);
      gload_lds16(kbase + ((long)kt * 64 + r) * (long)D + sw8(r, (lane & 15) * 8), &Ks[lr][0]);
    }
#pragma unroll
    for (int i = 0; i < 4; ++i) {
      const int lr = i * 32 + wid * 8;
      const int r  = lr + (lane >> 3);
      gload_lds16(vbase + (long)r * S + kt * 64 + sw8(r, (lane & 7) * 8), &Vs[lr][0]);
    }
    __syncthreads();

    f32x4_t sacc[4];
#pragma unroll
    for (int n = 0; n < 4; ++n)
#pragma unroll
      for (int r = 0; r < 4; ++r) sacc[n][r] = 0.f;

#pragma unroll
    for (int kk = 0; kk < 4; ++kk) {
      bf16x8_t bk[4];
#pragma unroll
      for (int n = 0; n < 4; ++n) {
        const int krow = n * 16 + frow;
        bk[n] = *reinterpret_cast<const bf16x8_t*>(&Ks[krow][sw8(krow, kk * 32 + fk8)]);
      }
#pragma unroll
      for (int n = 0; n < 4; ++n)
        sacc[n] = __builtin_amdgcn_mfma_f32_16x16x32_bf16(aq[kk], bk[n], sacc[n], 0, 0, 0);
    }

    const float tb = slope2 * (float)(kt << 6);
    float cbn[4];
#pragma unroll
    for (int n = 0; n < 4; ++n) cbn[n] = tb + cw[n];

    float tmax[4];
#pragma unroll
    for (int r = 0; r < 4; ++r) tmax[r] = -3.0e38f;

    if (kt == qb) {
#pragma unroll
      for (int n = 0; n < 4; ++n)
#pragma unroll
        for (int r = 0; r < 4; ++r) {
          float v = sacc[n][r] + cbn[n];
          v = (n * 16 + ocol <= wid * 16 + orow + r) ? v : -1.0e30f;
          sacc[n][r] = v;
          tmax[r] = fmaxf(tmax[r], v);
        }
    } else {
#pragma unroll
      for (int n = 0; n < 4; ++n)
#pragma unroll
        for (int r = 0; r < 4; ++r) {
          const float v = sacc[n][r] + cbn[n];
          sacc[n][r] = v;
          tmax[r] = fmaxf(tmax[r], v);
        }
    }
#pragma unroll
    for (int r = 0; r < 4; ++r) {
      float t = tmax[r];
      t = fmaxf(t, __shfl_xor(t, 1));
      t = fmaxf(t, __shfl_xor(t, 2));
      t = fmaxf(t, __shfl_xor(t, 4));
      t = fmaxf(t, __shfl_xor(t, 8));
      tmax[r] = t;
    }

#pragma unroll
    for (int r = 0; r < 4; ++r) {
      const float mnew = fmaxf(Mrun[r], tmax[r]);
      const float alpha = exp2f(Mrun[r] - mnew);
      Mrun[r] = mnew;
      lrun[r] *= alpha;
#pragma unroll
      for (int no = 0; no < 8; ++no) oacc[no][r] *= alpha;
    }

    float tsum[4];
#pragma unroll
    for (int r = 0; r < 4; ++r) tsum[r] = 0.f;
#pragma unroll
    for (int n = 0; n < 4; ++n)
#pragma unroll
      for (int r = 0; r < 4; ++r) {
        const float p = exp2f(sacc[n][r] - Mrun[r]);
        tsum[r] += p;
        const int prow = wid * 16 + orow + r;
        Ps[prow][sw8(prow, n * 16 + ocol)] = f2bf(p);
      }
#pragma unroll
    for (int r = 0; r < 4; ++r) {
      float t = tsum[r];
      t += __shfl_xor(t, 1);
      t += __shfl_xor(t, 2);
      t += __shfl_xor(t, 4);
      t += __shfl_xor(t, 8);
      lrun[r] += t;
    }

    __syncthreads();

#pragma unroll
    for (int kk = 0; kk < 2; ++kk) {
      const int prow = wid * 16 + frow;
      bf16x8_t pa = *reinterpret_cast<const bf16x8_t*>(&Ps[prow][sw8(prow, kk * 32 + fk8)]);
#pragma unroll
      for (int no = 0; no < 8; ++no) {
        const int vrow = no * 16 + frow;
        bf16x8_t bv = *reinterpret_cast<const bf16x8_t*>(&Vs[vrow][sw8(vrow, kk * 32 + fk8)]);
        oacc[no] = __builtin_amdgcn_mfma_f32_16x16x32_bf16(pa, bv, oacc[no], 0, 0, 0);
      }
    }
  }

#pragma unroll
  for (int r = 0; r < 4; ++r) {
    const float rl = 1.0f / lrun[r];
    const long trow = qrow0 + orow + r;
#pragma unroll
    for (int no = 0; no < 8; ++no)
      Out[trow * (long)D + h * Dh + no * 16 + ocol] = f2bf(oacc[no][r] * rl);
  }
}

// ---- launch --------------------------------------------------------------

extern "C" void kernel_launch(void* const* d_in, const int* in_sizes, int n_in,
                              void* d_out, int out_size, void* d_ws, size_t ws_size,
                              hipStream_t stream) {
  const float* hs   = (const float*)d_in[0];
  const float* qkvw = (const float*)d_in[1];
  const float* ow   = (const float*)d_in[2];

  const int D = 2048, B = 2, H = 16;
  const long TD = (long)in_sizes[0];   // T*D = 8388608
  const long DD = (long)in_sizes[2];   // D*D = 4194304
  const int T = (int)(TD / D);         // 4096
  const int S = T / B;                 // 2048
  const int Dh = D / H;                // 128
  const float log2e = 1.44269504f;
  const float qs = (1.0f / sqrtf((float)Dh)) * log2e;  // Q prescale

  u16* ws  = (u16*)d_ws;
  u16* hsb = ws;                  // TD    (later reused as attn)
  u16* wt  = ws + TD;             // 3*DD  (later reused as vt)
  u16* owt = wt + 3 * DD;         // DD
  u16* qkv = owt + DD;            // 3*TD  [Q | K | V]
  u16* vt   = wt;                 // TD    (overlay; wt dead after QKV GEMM)
  u16* attn = hsb;                // TD    (overlay; hsb dead after QKV GEMM)

  // 1) hidden -> bf16
  k_cast_bf16<<<dim3((unsigned)(TD / 1024)), 256, 0, stream>>>(hs, hsb, TD);
  // 2) qkv weights: cast + transpose to [3][E][D] (== fused Bt [6144][2048])
  k_transpose_cast<<<dim3(D / 32, D / 32, 3), 256, 0, stream>>>(qkvw, wt, D, D);
  // 3) o_proj weight: cast + transpose to [E][D]
  k_transpose_cast<<<dim3(D / 32, D / 32, 1), 256, 0, stream>>>(ow, owt, D, D);
  // 4) fused QKV projection (Q prescaled by sm_scale*log2e in epilogue)
  k_gemm8<u16><<<dim3((3 * D) / 256, T / 256), 512, 0, stream>>>(
      hsb, wt, qkv, T, 3 * D, D, TD, qs);
  // 5) V -> Vt[bh][Dh][S]
  k_transpose_v<<<dim3(S / 32, Dh / 32, B * H), 256, 0, stream>>>(
      qkv + 2 * TD, vt, S, D, Dh, H);
  // 6) attention (QBLK=64, log2 domain)
  k_attn<<<dim3(S / 64, B * H), 256, 0, stream>>>(
      qkv, qkv + TD, vt, attn, B, S, H, D, log2e);
  // 7) output projection -> f32 d_out (128x256 tiles: 8x32 = 256 blocks = 1 round)
  k_gemm2<float><<<dim3(D / 256, T / 128), 512, 0, stream>>>(
      attn, owt, (float*)d_out, T, D, D, 0L, 1.0f);
}